// Round 9
// baseline (1171.701 us; speedup 1.0000x reference)
//
#include <hip/hip_runtime.h>
#include <hip/hip_cooperative_groups.h>
#include <math.h>

namespace cg = cooperative_groups;

#define BATCH 16384
#define B6 (BATCH*6)
#define DT 0.01f

using half8_t = __attribute__((ext_vector_type(8))) _Float16;
using half4_t = __attribute__((ext_vector_type(4))) _Float16;
using half2_t = __attribute__((ext_vector_type(2))) _Float16;
using f32x4   = __attribute__((ext_vector_type(4))) float;

__device__ __constant__ float c_LOWER[6]  = {-6.28f,-6.28f,-3.14f,-6.28f,-6.28f,-6.28f};
__device__ __constant__ float c_UPPER[6]  = { 6.28f, 6.28f, 3.14f, 6.28f, 6.28f, 6.28f};
__device__ __constant__ float c_EFFORT[6] = {150.0f,150.0f,150.0f,28.0f,28.0f,28.0f};
__device__ __constant__ int   c_ROWOFF[6] = {0,1,3,6,10,15};

__device__ __forceinline__ float sp_f(float z){
  return fmaxf(z,0.0f) + __logf(1.0f + __expf(-fabsf(z)));
}
__device__ __forceinline__ float sig_f(float z){
  return __builtin_amdgcn_rcpf(1.0f + __expf(-z));
}

__device__ __forceinline__ float4 f4all(float v){ return make_float4(v,v,v,v); }
__device__ __forceinline__ void fma4(float4& acc, float w, float4 a){
  acc.x=fmaf(w,a.x,acc.x); acc.y=fmaf(w,a.y,acc.y); acc.z=fmaf(w,a.z,acc.z); acc.w=fmaf(w,a.w,acc.w);
}
__device__ __forceinline__ float4 sp4(float4 z){
  return make_float4(sp_f(z.x),sp_f(z.y),sp_f(z.z),sp_f(z.w));
}
__device__ __forceinline__ float4 sig4(float4 z){
  return make_float4(sig_f(z.x),sig_f(z.y),sig_f(z.z),sig_f(z.w));
}

// XOR-swizzled accessors for sh_t [12][16] (r3/r4-verified conflict-free)
__device__ __forceinline__ const float4* chunkc(const float (*arr)[16], int n, int cc){
  return reinterpret_cast<const float4*>(&arr[n][4*(cc ^ ((n>>1)&3))]);
}
__device__ __forceinline__ float& el(float (*arr)[16], int n, int s){
  return arr[n][4*((s>>2) ^ ((n>>1)&3)) + (s&3)];
}

// ---- MFMA helpers --------------------------------------------------------
__device__ __forceinline__ f32x4 mfma3(half8_t ah, half8_t al, half8_t bh, half8_t bl, f32x4 acc){
  acc = __builtin_amdgcn_mfma_f32_16x16x32_f16(ah, bh, acc, 0,0,0);
  acc = __builtin_amdgcn_mfma_f32_16x16x32_f16(ah, bl, acc, 0,0,0);
  acc = __builtin_amdgcn_mfma_f32_16x16x32_f16(al, bh, acc, 0,0,0);
  return acc;
}
__device__ __forceinline__ half8_t ldB(const _Float16 (*B)[136], int n, int q, int quad){
  return *reinterpret_cast<const half8_t*>(&B[n][q*32 + quad*8]);
}
__device__ __forceinline__ void stB4(_Float16 (*Bh)[136], _Float16 (*Bl)[136], int n, int base, float4 v){
  half4_t hi, lo;
  const float* p = &v.x;
  #pragma unroll
  for (int j=0;j<4;j++){ hi[j] = (_Float16)p[j]; lo[j] = (_Float16)(p[j] - (float)hi[j]); }
  *reinterpret_cast<half4_t*>(&Bh[n][base]) = hi;
  *reinterpret_cast<half4_t*>(&Bl[n][base]) = lo;
}
__device__ __forceinline__ void stB2(_Float16 (*Bh)[136], _Float16 (*Bl)[136], int n, int k2, float a, float b){
  half2_t hi, lo;
  hi[0]=(_Float16)a; hi[1]=(_Float16)b;
  lo[0]=(_Float16)(a-(float)hi[0]); lo[1]=(_Float16)(b-(float)hi[1]);
  *reinterpret_cast<half2_t*>(&Bh[n][k2]) = hi;
  *reinterpret_cast<half2_t*>(&Bl[n][k2]) = lo;
}

// ---- shared-memory layout (union'd regions, ~31.4 KB) --------------------
struct SmemT {
  alignas(16) char u[8704];                 // Bact[2][16][136] | dy[42][17] | dv[12][17]
  alignas(16) _Float16 Bd[2][2][16][136];
  alignas(16) float t[12][16];
  float y[21][17];
  float wg[2][6][16];
  float qd[6][16], tau[6][16], f[6][16];
  float c[6][16], grav[6][16], v[6][16];
};

// ---------------- init: transposes + split-fp16 A-fragments + stage-0 viol
// frag regions (in halves): W2L @0, W2V @16384, W2V^T @32768, W3L @49152,
// W1V^T @53248 (rows 12..15 zero-padded). viol must be pre-zeroed (memset).
__global__ void __launch_bounds__(256) k_init(
    const float* __restrict__ obs,
    const float* __restrict__ W1L, const float* __restrict__ W2L,
    const float* __restrict__ W3L, const float* __restrict__ W1V,
    const float* __restrict__ W2V, const float* __restrict__ b3L,
    float* __restrict__ W1LT, float* __restrict__ W1VT, float* __restrict__ b3Lp,
    _Float16* __restrict__ fragHi, _Float16* __restrict__ fragLo, int* __restrict__ viol)
{
  int t = blockIdx.x*256 + threadIdx.x;
  if (t < 1536){ int i = t/128, k = t%128; W1LT[t] = W1L[k*12+i]; W1VT[t] = W1V[k*12+i]; }
  if (t < 32) b3Lp[t] = (t < 21) ? b3L[t] : 0.0f;
  if (t < 6912){
    int kind, f;
    if (t < 2048){ kind=0; f=t; }
    else if (t < 4096){ kind=1; f=t-2048; }
    else if (t < 6144){ kind=2; f=t-4096; }
    else if (t < 6656){ kind=3; f=t-6144; }
    else { kind=4; f=t-6656; }
    int tile = f>>8, q = (f>>6)&3, l = f&63, m = l&15, kq = 8*(l>>4);
    int off = (kind==0?0:kind==1?16384:kind==2?32768:kind==3?49152:53248) + f*8;
    #pragma unroll
    for (int e=0;e<8;e++){
      float v;
      int kk = 32*q + kq + e;
      if (kind==0)      v = W2L[(16*tile+m)*128 + kk];
      else if (kind==1) v = W2V[(16*tile+m)*128 + kk];
      else if (kind==2) v = W2V[kk*128 + (16*tile+m)];
      else if (kind==3){ int r = 16*tile+m; v = (r<21) ? W3L[r*128 + kk] : 0.0f; }
      else              v = (m<12) ? W1V[kk*12 + m] : 0.0f;
      _Float16 hi = (_Float16)v;
      _Float16 lo = (_Float16)(v - (float)hi);
      fragHi[off+e] = hi; fragLo[off+e] = lo;
    }
  }
  // stage-0 viol ballot (viol pre-zeroed by hipMemsetAsync)
  {
    unsigned mask = 0;
    const float* o = obs + t*12;
    #pragma unroll
    for (int i=0;i<6;i++){
      float q = o[i];
      float lo = c_LOWER[i]+0.1f, up = c_UPPER[i]-0.1f;
      if (q <= lo || q >= up) mask |= (1u<<i);
    }
    unsigned wm = 0;
    #pragma unroll
    for (int i=0;i<6;i++) if (__ballot((int)((mask>>i)&1u))) wm |= (1u<<i);
    if ((threadIdx.x & 63)==0 && wm) atomicOr(viol, (int)wm);
  }
}

// ---------------- one RK4 stage (shared by coop and fallback paths) -------
__device__ __forceinline__ void stage_body(int stage, SmemT& sm,
    const float* __restrict__ obs,
    float* __restrict__ q_cur, float* __restrict__ qd_cur,
    const float* __restrict__ action,
    const float* __restrict__ W1LT, const float* __restrict__ b1L,
    const float* __restrict__ b2L,  const float* __restrict__ b3Lp,
    const float* __restrict__ W1VT, const float* __restrict__ b1V,
    const float* __restrict__ b2V,  const float* __restrict__ W3V,
    const float* __restrict__ W1V,
    const _Float16* __restrict__ fragHi, const _Float16* __restrict__ fragLo,
    int* __restrict__ viol, float* __restrict__ kqd, float* __restrict__ out)
{
  auto Bact = reinterpret_cast<_Float16 (*)[16][136]>(sm.u);  // [2][16][136]
  auto dyp  = reinterpret_cast<float (*)[17]>(sm.u);          // [42][17]
  auto dvp  = reinterpret_cast<float (*)[17]>(sm.u);          // [12][17]

  const int tid = threadIdx.x;
  const int l = tid & 63;
  const int w = tid >> 6;
  const int lane_n = l & 15;
  const int quad = l >> 4;
  const int base0 = w*16 + quad*4;
  const int base1 = (w+4)*16 + quad*4;
  const int s0 = blockIdx.x * 16;
  const int vm = __hip_atomic_load(viol + stage, __ATOMIC_RELAXED, __HIP_MEMORY_SCOPE_AGENT);

  const half8_t* fW2Lh  = (const half8_t*)(fragHi);
  const half8_t* fW2Ll  = (const half8_t*)(fragLo);
  const half8_t* fW2Vh  = (const half8_t*)(fragHi + 16384);
  const half8_t* fW2Vl  = (const half8_t*)(fragLo + 16384);
  const half8_t* fW2VTh = (const half8_t*)(fragHi + 32768);
  const half8_t* fW2VTl = (const half8_t*)(fragLo + 32768);
  const half8_t* fW3h   = (const half8_t*)(fragHi + 49152);
  const half8_t* fW3l   = (const half8_t*)(fragLo + 49152);
  const half8_t* fW1Th  = (const half8_t*)(fragHi + 53248);
  const half8_t* fW1Tl  = (const half8_t*)(fragLo + 53248);

  // ---- phase 0: trig, tau, constraint force
  if (tid < 96){
    int s = tid & 15, i = tid >> 4;
    float q, qdv;
    if (stage == 0){ q = obs[(s0+s)*12 + i]; qdv = obs[(s0+s)*12 + 6 + i]; }
    else           { q = q_cur[(s0+s)*6 + i]; qdv = qd_cur[(s0+s)*6 + i]; }
    sm.qd[i][s] = qdv;
    sm.tau[i][s] = action[(s0+s)*6+i] * c_EFFORT[i];
    el(sm.t, 2*i,   s) = cosf(q);
    el(sm.t, 2*i+1, s) = sinf(q);
    float lo = c_LOWER[i]+0.1f, up = c_UPPER[i]-0.1f;
    float barrier = -5.0f*(1.0f/(q-lo) - 1.0f/(up-q));
    float clip = (q<=lo)? c_EFFORT[i] : ((q>=up)? -c_EFFORT[i] : 0.0f);
    sm.f[i][s] = ((vm>>i)&1) ? clip : barrier;
    sm.c[i][s] = 0.0f;
  }
  __syncthreads();

  float4 s1a, s1b;
  // ---- L1L (VALU) -> Bact
  {
    float2 bb = *reinterpret_cast<const float2*>(b1L + 2*l);
    float4 z0 = f4all(bb.x), z1 = f4all(bb.y);
    #pragma unroll
    for (int i=0;i<12;i++){
      float2 wv = *reinterpret_cast<const float2*>(W1LT + i*128 + 2*l);
      float4 a = *chunkc(sm.t, i, w);
      fma4(z0, wv.x, a); fma4(z1, wv.y, a);
    }
    float4 h0 = sp4(z0), h1 = sp4(z1);
    s1a = sig4(z0); s1b = sig4(z1);
    #pragma unroll
    for (int j=0;j<4;j++)
      stB2(Bact[0], Bact[1], 4*w+j, 2*l, (&h0.x)[j], (&h1.x)[j]);
  }
  __syncthreads();

  float4 s2a, s2b;
  // ---- L2L MFMA + epilogue (h2 -> Bact in-place)
  {
    f32x4 acc0 = {0.f,0.f,0.f,0.f}, acc1 = {0.f,0.f,0.f,0.f};
    #pragma unroll
    for (int q=0;q<4;q++){
      half8_t bh = ldB(Bact[0], lane_n, q, quad);
      half8_t bl = ldB(Bact[1], lane_n, q, quad);
      acc0 = mfma3(fW2Lh[(w*4+q)*64+l],     fW2Ll[(w*4+q)*64+l],     bh, bl, acc0);
      acc1 = mfma3(fW2Lh[((w+4)*4+q)*64+l], fW2Ll[((w+4)*4+q)*64+l], bh, bl, acc1);
    }
    __syncthreads();
    float4 ba = *reinterpret_cast<const float4*>(b2L + base0);
    float4 bb = *reinterpret_cast<const float4*>(b2L + base1);
    float4 h2a, h2b;
    #pragma unroll
    for (int j=0;j<4;j++){
      float z = acc0[j] + (&ba.x)[j];
      (&h2a.x)[j] = sp_f(z); (&s2a.x)[j] = sig_f(z);
      z = acc1[j] + (&bb.x)[j];
      (&h2b.x)[j] = sp_f(z); (&s2b.x)[j] = sig_f(z);
    }
    stB4(Bact[0], Bact[1], lane_n, base0, h2a);
    stB4(Bact[0], Bact[1], lane_n, base1, h2b);
  }
  __syncthreads();

  // ---- L3 MFMA (waves 0,1) -> y only (s3 recomputed later via identity)
  if (w < 2){
    f32x4 acc = {0.f,0.f,0.f,0.f};
    #pragma unroll
    for (int q=0;q<4;q++){
      half8_t bh = ldB(Bact[0], lane_n, q, quad);
      half8_t bl = ldB(Bact[1], lane_n, q, quad);
      acc = mfma3(fW3h[(w*4+q)*64+l], fW3l[(w*4+q)*64+l], bh, bl, acc);
    }
    int rb = w*16 + quad*4;
    #pragma unroll
    for (int j=0;j<4;j++){
      int r = rb + j;
      if (r < 21) sm.y[r][lane_n] = sp_f(acc[j] + b3Lp[r]);
    }
  }
  __syncthreads();

  // ---- v = L^T qdot
  if (tid < 96){
    int s = tid & 15, jj = tid >> 4;
    float acc = 0.f;
    for (int i=jj;i<6;i++) acc = fmaf(sm.y[c_ROWOFF[i]+jj][s], sm.qd[i][s], acc);
    sm.v[jj][s] = acc;
  }

  // ---- tangent groups: dirs {2G, 2G+1}
  for (int G=0; G<3; ++G){
    #pragma unroll
    for (int d=0; d<2; ++d){
      int g = 2*G + d;
      float2 w0 = *reinterpret_cast<const float2*>(W1LT + (2*g)*128 + 2*l);
      float2 w1 = *reinterpret_cast<const float2*>(W1LT + (2*g+1)*128 + 2*l);
      float4 tc = *chunkc(sm.t, 2*g,   w);
      float4 ts = *chunkc(sm.t, 2*g+1, w);
      #pragma unroll
      for (int j=0;j<4;j++){
        float tcj = (&tc.x)[j], tsj = (&ts.x)[j];
        float d0 = (&s1a.x)[j]*(tcj*w1.x - tsj*w0.x);
        float d1 = (&s1b.x)[j]*(tcj*w1.y - tsj*w0.y);
        stB2(sm.Bd[d][0], sm.Bd[d][1], 4*w+j, 2*l, d0, d1);
      }
    }
    __syncthreads();
    f32x4 ta00={0.f,0.f,0.f,0.f}, ta01=ta00, ta10=ta00, ta11=ta00;
    #pragma unroll
    for (int q=0;q<4;q++){
      half8_t b0h = ldB(sm.Bd[0][0], lane_n, q, quad);
      half8_t b0l = ldB(sm.Bd[0][1], lane_n, q, quad);
      half8_t b1h = ldB(sm.Bd[1][0], lane_n, q, quad);
      half8_t b1l = ldB(sm.Bd[1][1], lane_n, q, quad);
      half8_t a0h = fW2Lh[(w*4+q)*64+l],     a0l = fW2Ll[(w*4+q)*64+l];
      half8_t a1h = fW2Lh[((w+4)*4+q)*64+l], a1l = fW2Ll[((w+4)*4+q)*64+l];
      ta00 = mfma3(a0h, a0l, b0h, b0l, ta00);
      ta01 = mfma3(a0h, a0l, b1h, b1l, ta01);
      ta10 = mfma3(a1h, a1l, b0h, b0l, ta10);
      ta11 = mfma3(a1h, a1l, b1h, b1l, ta11);
    }
    __syncthreads();
    {
      float4 v;
      #pragma unroll
      for (int j=0;j<4;j++) (&v.x)[j] = (&s2a.x)[j]*ta00[j];
      stB4(sm.Bd[0][0], sm.Bd[0][1], lane_n, base0, v);
      #pragma unroll
      for (int j=0;j<4;j++) (&v.x)[j] = (&s2b.x)[j]*ta10[j];
      stB4(sm.Bd[0][0], sm.Bd[0][1], lane_n, base1, v);
      #pragma unroll
      for (int j=0;j<4;j++) (&v.x)[j] = (&s2a.x)[j]*ta01[j];
      stB4(sm.Bd[1][0], sm.Bd[1][1], lane_n, base0, v);
      #pragma unroll
      for (int j=0;j<4;j++) (&v.x)[j] = (&s2b.x)[j]*ta11[j];
      stB4(sm.Bd[1][0], sm.Bd[1][1], lane_n, base1, v);
    }
    __syncthreads();
    {
      int d = w & 1, tt = w >> 1;
      f32x4 acc = {0.f,0.f,0.f,0.f};
      #pragma unroll
      for (int q=0;q<4;q++){
        half8_t bh = ldB(sm.Bd[d][0], lane_n, q, quad);
        half8_t bl = ldB(sm.Bd[d][1], lane_n, q, quad);
        acc = mfma3(fW3h[(tt*4+q)*64+l], fW3l[(tt*4+q)*64+l], bh, bl, acc);
      }
      int rb = tt*16 + quad*4;
      #pragma unroll
      for (int j=0;j<4;j++){
        int r = rb + j;
        if (r < 21){
          float s3 = 1.0f - __expf(-sm.y[r][lane_n]);   // sig(z)=1-exp(-sp(z))
          dyp[d*21 + r][lane_n] = s3 * acc[j];
        }
      }
    }
    __syncthreads();
    if (tid < 32){
      int s = tid & 15, gg = tid >> 4;
      float qd[6];
      #pragma unroll
      for (int i=0;i<6;i++) qd[i] = sm.qd[i][s];
      float u[6];
      #pragma unroll
      for (int jj=0;jj<6;jj++){
        float acc = 0.f;
        for (int i=jj;i<6;i++) acc = fmaf(dyp[gg*21 + c_ROWOFF[i]+jj][s], qd[i], acc);
        u[jj] = acc;
      }
      #pragma unroll
      for (int i=0;i<6;i++){
        float acc = 0.f;
        for (int j=0;j<=i;j++){
          acc = fmaf(dyp[gg*21 + c_ROWOFF[i]+j][s], sm.v[j][s], acc);
          acc = fmaf(sm.y[c_ROWOFF[i]+j][s], u[j], acc);
        }
        sm.wg[gg][i][s] = acc;
      }
    }
    __syncthreads();
    if (tid < 96){
      int s = tid & 15, i = tid >> 4;
      float acc = sm.c[i][s];
      acc = fmaf(sm.qd[2*G][s],   sm.wg[0][i][s], acc);
      acc = fmaf(sm.qd[2*G+1][s], sm.wg[1][i][s], acc);
      int gi = i - 2*G;
      if (gi == 0 || gi == 1){
        float r = 0.f;
        #pragma unroll
        for (int j=0;j<6;j++) r = fmaf(sm.qd[j][s], sm.wg[gi][j][s], r);
        acc -= 0.5f*r;
      }
      sm.c[i][s] = acc;
    }
    __syncthreads();
  }

  // ---- V-net L1 (VALU) -> Bact (dy dead)
  {
    float2 bb = *reinterpret_cast<const float2*>(b1V + 2*l);
    float4 z0 = f4all(bb.x), z1 = f4all(bb.y);
    #pragma unroll
    for (int i=0;i<12;i++){
      float2 wv = *reinterpret_cast<const float2*>(W1VT + i*128 + 2*l);
      float4 a = *chunkc(sm.t, i, w);
      fma4(z0, wv.x, a); fma4(z1, wv.y, a);
    }
    float4 h0 = sp4(z0), h1 = sp4(z1);
    #pragma unroll
    for (int j=0;j<4;j++)
      stB2(Bact[0], Bact[1], 4*w+j, 2*l, (&h0.x)[j], (&h1.x)[j]);
  }
  __syncthreads();
  // ---- L2V MFMA; epilogue g2 = sig(z)*W3V -> Bact in-place
  {
    f32x4 acc0 = {0.f,0.f,0.f,0.f}, acc1 = {0.f,0.f,0.f,0.f};
    #pragma unroll
    for (int q=0;q<4;q++){
      half8_t bh = ldB(Bact[0], lane_n, q, quad);
      half8_t bl = ldB(Bact[1], lane_n, q, quad);
      acc0 = mfma3(fW2Vh[(w*4+q)*64+l],     fW2Vl[(w*4+q)*64+l],     bh, bl, acc0);
      acc1 = mfma3(fW2Vh[((w+4)*4+q)*64+l], fW2Vl[((w+4)*4+q)*64+l], bh, bl, acc1);
    }
    __syncthreads();
    float4 ba  = *reinterpret_cast<const float4*>(b2V + base0);
    float4 bb  = *reinterpret_cast<const float4*>(b2V + base1);
    float4 w3a = *reinterpret_cast<const float4*>(W3V + base0);
    float4 w3b = *reinterpret_cast<const float4*>(W3V + base1);
    float4 g2a, g2b;
    #pragma unroll
    for (int j=0;j<4;j++){
      (&g2a.x)[j] = sig_f(acc0[j] + (&ba.x)[j]) * (&w3a.x)[j];
      (&g2b.x)[j] = sig_f(acc1[j] + (&bb.x)[j]) * (&w3b.x)[j];
    }
    stB4(Bact[0], Bact[1], lane_n, base0, g2a);
    stB4(Bact[0], Bact[1], lane_n, base1, g2b);
  }
  __syncthreads();
  // ---- V bwd MFMA (A = W2V^T); epilogue: recompute s1V, g1 -> Bd[0]
  {
    f32x4 acc0 = {0.f,0.f,0.f,0.f}, acc1 = {0.f,0.f,0.f,0.f};
    #pragma unroll
    for (int q=0;q<4;q++){
      half8_t bh = ldB(Bact[0], lane_n, q, quad);
      half8_t bl = ldB(Bact[1], lane_n, q, quad);
      acc0 = mfma3(fW2VTh[(w*4+q)*64+l],     fW2VTl[(w*4+q)*64+l],     bh, bl, acc0);
      acc1 = mfma3(fW2VTh[((w+4)*4+q)*64+l], fW2VTl[((w+4)*4+q)*64+l], bh, bl, acc1);
    }
    float tn[12];
    #pragma unroll
    for (int i=0;i<12;i++) tn[i] = el(sm.t, i, lane_n);
    float4 g1a, g1b;
    #pragma unroll
    for (int j=0;j<4;j++){
      int r = base0 + j;
      float z = b1V[r];
      const float* wr = W1V + r*12;
      #pragma unroll
      for (int i=0;i<12;i++) z = fmaf(wr[i], tn[i], z);
      (&g1a.x)[j] = sig_f(z) * acc0[j];
      r = base1 + j;
      z = b1V[r];
      wr = W1V + r*12;
      #pragma unroll
      for (int i=0;i<12;i++) z = fmaf(wr[i], tn[i], z);
      (&g1b.x)[j] = sig_f(z) * acc1[j];
    }
    stB4(sm.Bd[0][0], sm.Bd[0][1], lane_n, base0, g1a);
    stB4(sm.Bd[0][0], sm.Bd[0][1], lane_n, base1, g1b);
  }
  __syncthreads();
  // ---- dV/dt = W1V^T g1 via MFMA (wave 0; Bact dead -> dv overlay)
  if (w == 0){
    f32x4 acc = {0.f,0.f,0.f,0.f};
    #pragma unroll
    for (int q=0;q<4;q++){
      half8_t bh = ldB(sm.Bd[0][0], lane_n, q, quad);
      half8_t bl = ldB(sm.Bd[0][1], lane_n, q, quad);
      acc = mfma3(fW1Th[q*64+l], fW1Tl[q*64+l], bh, bl, acc);
    }
    int rb = quad*4;
    #pragma unroll
    for (int j=0;j<4;j++){
      int r = rb + j;
      if (r < 12) dvp[r][lane_n] = acc[j];
    }
  }
  __syncthreads();
  // ---- gravity
  if (tid < 96){
    int k = tid>>4, s = tid&15;
    sm.grav[k][s] = fmaf(el(sm.t,2*k,s), dvp[2*k+1][s],
                         -(el(sm.t,2*k+1,s)*dvp[2*k][s]));
  }
  __syncthreads();
  // ---- assembly + triangular solves + folded pre / final combine
  if (l < 4){
    int s = w*4 + l;
    float Lm[21];
    #pragma unroll
    for (int o=0;o<21;o++) Lm[o] = sm.y[o][s];
    float rhs[6];
    #pragma unroll
    for (int i=0;i<6;i++) rhs[i] = sm.tau[i][s] - sm.c[i][s] - sm.grav[i][s] - sm.f[i][s];
    float z[6];
    #pragma unroll
    for (int i=0;i<6;i++){
      float acc = rhs[i];
      for (int j=0;j<i;j++) acc = fmaf(-Lm[c_ROWOFF[i]+j], z[j], acc);
      z[i] = acc * __builtin_amdgcn_rcpf(Lm[c_ROWOFF[i]+i]);
    }
    float a[6];
    #pragma unroll
    for (int i=5;i>=0;i--){
      float acc = z[i];
      for (int j=i+1;j<6;j++) acc = fmaf(-Lm[c_ROWOFF[j]+i], a[j], acc);
      a[i] = acc * __builtin_amdgcn_rcpf(Lm[c_ROWOFF[i]+i]);
    }
    int b = s0 + s;
    const float* o = obs + b*12;
    if (stage < 3){
      float* kqd_out = kqd + stage*B6;
      #pragma unroll
      for (int i=0;i<6;i++) kqd_out[b*6+i] = a[i];
      unsigned mask = 0;
      #pragma unroll
      for (int i=0;i<6;i++){
        float q0=o[i], qd0=o[6+i];
        float q, qd;
        if (stage == 0){
          q  = q0 + 0.5f*DT*qd0;
          qd = qd0 + 0.5f*DT*a[i];
        } else if (stage == 1){
          float k1 = kqd[b*6+i];
          q  = q0 + 0.5f*DT*qd0 + 0.25f*DT*DT*k1;
          qd = qd0 + 0.5f*DT*a[i];
        } else {
          float k2 = kqd[B6 + b*6+i];
          q  = q0 + DT*qd0 + 0.5f*DT*DT*k2;
          qd = qd0 + DT*a[i];
        }
        q_cur[b*6+i]=q; qd_cur[b*6+i]=qd;
        float lo = c_LOWER[i]+0.1f, up = c_UPPER[i]-0.1f;
        if (q <= lo || q >= up) mask |= (1u<<i);
      }
      if (mask) atomicOr(viol + stage + 1, (int)mask);
    } else {
      // final RK4 combine: a == k4
      #pragma unroll
      for (int i=0;i<6;i++){
        float q0=o[i], qd0=o[6+i];
        float k1=kqd[b*6+i], k2=kqd[B6+b*6+i], k3=kqd[2*B6+b*6+i];
        float qn = q0 + DT*qd0 + (DT*DT/6.0f)*(k1+k2+k3);
        qn = fminf(fmaxf(qn, c_LOWER[i]), c_UPPER[i]);
        out[b*12+i] = qn;
        out[b*12+6+i] = qd0 + (DT/6.0f)*(k1 + 2.0f*k2 + 2.0f*k3 + a[i]);
      }
    }
  }
}

// ---------------- unified stage kernel ----------------
// Coop path: one launch (0,4) with grid.sync between stages.
// Fallback: four plain launches (s, s+1) — grid.sync never executes.
__global__ void __launch_bounds__(256, 4) k_stages(
    int s_begin, int s_end,
    const float* __restrict__ obs,
    float* __restrict__ q_cur, float* __restrict__ qd_cur,
    const float* __restrict__ action,
    const float* __restrict__ W1LT, const float* __restrict__ b1L,
    const float* __restrict__ b2L,  const float* __restrict__ b3Lp,
    const float* __restrict__ W1VT, const float* __restrict__ b1V,
    const float* __restrict__ b2V,  const float* __restrict__ W3V,
    const float* __restrict__ W1V,
    const _Float16* __restrict__ fragHi, const _Float16* __restrict__ fragLo,
    int* __restrict__ viol, float* __restrict__ kqd, float* __restrict__ out)
{
  __shared__ SmemT sm;
  for (int s = s_begin; s < s_end; ++s){
    stage_body(s, sm, obs, q_cur, qd_cur, action,
               W1LT, b1L, b2L, b3Lp, W1VT, b1V, b2V, W3V, W1V,
               fragHi, fragLo, viol, kqd, out);
    if (s + 1 < s_end){
      cg::this_grid().sync();
    }
  }
}

extern "C" void kernel_launch(void* const* d_in, const int* in_sizes, int n_in,
                              void* d_out, int out_size, void* d_ws, size_t ws_size,
                              hipStream_t stream) {
  const float* obs    = (const float*)d_in[0];
  const float* action = (const float*)d_in[1];
  const float* W1L = (const float*)d_in[2];  const float* b1L = (const float*)d_in[3];
  const float* W2L = (const float*)d_in[4];  const float* b2L = (const float*)d_in[5];
  const float* W3L = (const float*)d_in[6];  const float* b3L = (const float*)d_in[7];
  const float* W1V = (const float*)d_in[8];  const float* b1V = (const float*)d_in[9];
  const float* W2V = (const float*)d_in[10]; const float* b2V = (const float*)d_in[11];
  const float* W3V = (const float*)d_in[12]; // b3V unused: only grad of V needed

  float* ws = (float*)d_ws;
  _Float16* fragHi = (_Float16*)ws;            // 55296 halves
  _Float16* fragLo = fragHi + 55296;           // 55296 halves
  float* W1LT  = ws + 55296;                   // 1536
  float* W1VT  = W1LT + 1536;                  // 1536
  float* b3Lp  = W1VT + 1536;                  // 32
  float* q_cur  = b3Lp + 32;                   // B6
  float* qd_cur = q_cur + B6;                  // B6
  float* kqd    = qd_cur + B6;                 // 3*B6
  int*   viol   = (int*)(kqd + 3*B6);          // 4

  float* out = (float*)d_out;

  hipMemsetAsync(viol, 0, 16, stream);
  k_init<<<64,256,0,stream>>>(obs, W1L, W2L, W3L, W1V, W2V, b3L,
                              W1LT, W1VT, b3Lp, fragHi, fragLo, viol);

  int sb = 0, se = 4;
  void* args[] = {
    (void*)&sb, (void*)&se,
    (void*)&obs, (void*)&q_cur, (void*)&qd_cur, (void*)&action,
    (void*)&W1LT, (void*)&b1L, (void*)&b2L, (void*)&b3Lp,
    (void*)&W1VT, (void*)&b1V, (void*)&b2V, (void*)&W3V, (void*)&W1V,
    (void*)&fragHi, (void*)&fragLo,
    (void*)&viol, (void*)&kqd, (void*)&out
  };
  hipError_t err = hipLaunchCooperativeKernel((const void*)k_stages,
                                              dim3(1024), dim3(256),
                                              args, 0, stream);
  if (err != hipSuccess){
    (void)hipGetLastError();  // clear sticky error
    for (int s = 0; s < 4; ++s){
      k_stages<<<1024,256,0,stream>>>(s, s+1, obs, q_cur, qd_cur, action,
          W1LT, b1L, b2L, b3Lp, W1VT, b1V, b2V, W3V, W1V,
          fragHi, fragLo, viol, kqd, out);
    }
  }
}

// Round 10
// 973.474 us; speedup vs baseline: 1.2036x; 1.2036x over previous
//
#include <hip/hip_runtime.h>
#include <hip/hip_cooperative_groups.h>
#include <math.h>

namespace cg = cooperative_groups;

#define BATCH 16384
#define B6 (BATCH*6)
#define DT 0.01f
#define NTILES 1024

using half8_t = __attribute__((ext_vector_type(8))) _Float16;
using half4_t = __attribute__((ext_vector_type(4))) _Float16;
using half2_t = __attribute__((ext_vector_type(2))) _Float16;
using f32x4   = __attribute__((ext_vector_type(4))) float;

__device__ __constant__ float c_LOWER[6]  = {-6.28f,-6.28f,-3.14f,-6.28f,-6.28f,-6.28f};
__device__ __constant__ float c_UPPER[6]  = { 6.28f, 6.28f, 3.14f, 6.28f, 6.28f, 6.28f};
__device__ __constant__ float c_EFFORT[6] = {150.0f,150.0f,150.0f,28.0f,28.0f,28.0f};
__device__ __constant__ int   c_ROWOFF[6] = {0,1,3,6,10,15};

__device__ __forceinline__ float sp_f(float z){
  return fmaxf(z,0.0f) + __logf(1.0f + __expf(-fabsf(z)));
}
__device__ __forceinline__ float sig_f(float z){
  return __builtin_amdgcn_rcpf(1.0f + __expf(-z));
}

__device__ __forceinline__ float4 f4all(float v){ return make_float4(v,v,v,v); }
__device__ __forceinline__ void fma4(float4& acc, float w, float4 a){
  acc.x=fmaf(w,a.x,acc.x); acc.y=fmaf(w,a.y,acc.y); acc.z=fmaf(w,a.z,acc.z); acc.w=fmaf(w,a.w,acc.w);
}
__device__ __forceinline__ float4 sp4(float4 z){
  return make_float4(sp_f(z.x),sp_f(z.y),sp_f(z.z),sp_f(z.w));
}
__device__ __forceinline__ float4 sig4(float4 z){
  return make_float4(sig_f(z.x),sig_f(z.y),sig_f(z.z),sig_f(z.w));
}

// XOR-swizzled accessors for sh_t [12][16] (r3/r4-verified conflict-free)
__device__ __forceinline__ const float4* chunkc(const float (*arr)[16], int n, int cc){
  return reinterpret_cast<const float4*>(&arr[n][4*(cc ^ ((n>>1)&3))]);
}
__device__ __forceinline__ float& el(float (*arr)[16], int n, int s){
  return arr[n][4*((s>>2) ^ ((n>>1)&3)) + (s&3)];
}

// ---- MFMA helpers --------------------------------------------------------
__device__ __forceinline__ f32x4 mfma3(half8_t ah, half8_t al, half8_t bh, half8_t bl, f32x4 acc){
  acc = __builtin_amdgcn_mfma_f32_16x16x32_f16(ah, bh, acc, 0,0,0);
  acc = __builtin_amdgcn_mfma_f32_16x16x32_f16(ah, bl, acc, 0,0,0);
  acc = __builtin_amdgcn_mfma_f32_16x16x32_f16(al, bh, acc, 0,0,0);
  return acc;
}
__device__ __forceinline__ half8_t ldB(const _Float16 (*B)[136], int n, int q, int quad){
  return *reinterpret_cast<const half8_t*>(&B[n][q*32 + quad*8]);
}
__device__ __forceinline__ void stB4(_Float16 (*Bh)[136], _Float16 (*Bl)[136], int n, int base, float4 v){
  half4_t hi, lo;
  const float* p = &v.x;
  #pragma unroll
  for (int j=0;j<4;j++){ hi[j] = (_Float16)p[j]; lo[j] = (_Float16)(p[j] - (float)hi[j]); }
  *reinterpret_cast<half4_t*>(&Bh[n][base]) = hi;
  *reinterpret_cast<half4_t*>(&Bl[n][base]) = lo;
}
__device__ __forceinline__ void stB2(_Float16 (*Bh)[136], _Float16 (*Bl)[136], int n, int k2, float a, float b){
  half2_t hi, lo;
  hi[0]=(_Float16)a; hi[1]=(_Float16)b;
  lo[0]=(_Float16)(a-(float)hi[0]); lo[1]=(_Float16)(b-(float)hi[1]);
  *reinterpret_cast<half2_t*>(&Bh[n][k2]) = hi;
  *reinterpret_cast<half2_t*>(&Bl[n][k2]) = lo;
}

// ---- shared-memory layout (union'd regions, ~31.4 KB) --------------------
struct SmemT {
  alignas(16) char u[8704];                 // Bact[2][16][136] | dy[42][17] | dv[12][17]
  alignas(16) _Float16 Bd[2][2][16][136];
  alignas(16) float t[12][16];
  float y[21][17];
  float wg[2][6][16];
  float qd[6][16], tau[6][16], f[6][16];
  float c[6][16], grav[6][16], v[6][16];
};

// ---------------- init: transposes + split-fp16 A-fragments + stage-0 viol
__global__ void __launch_bounds__(256) k_init(
    const float* __restrict__ obs,
    const float* __restrict__ W1L, const float* __restrict__ W2L,
    const float* __restrict__ W3L, const float* __restrict__ W1V,
    const float* __restrict__ W2V, const float* __restrict__ b3L,
    float* __restrict__ W1LT, float* __restrict__ W1VT, float* __restrict__ b3Lp,
    _Float16* __restrict__ fragHi, _Float16* __restrict__ fragLo, int* __restrict__ viol)
{
  int t = blockIdx.x*256 + threadIdx.x;
  if (t < 1536){ int i = t/128, k = t%128; W1LT[t] = W1L[k*12+i]; W1VT[t] = W1V[k*12+i]; }
  if (t < 32) b3Lp[t] = (t < 21) ? b3L[t] : 0.0f;
  if (t < 6912){
    int kind, f;
    if (t < 2048){ kind=0; f=t; }
    else if (t < 4096){ kind=1; f=t-2048; }
    else if (t < 6144){ kind=2; f=t-4096; }
    else if (t < 6656){ kind=3; f=t-6144; }
    else { kind=4; f=t-6656; }
    int tile = f>>8, q = (f>>6)&3, l = f&63, m = l&15, kq = 8*(l>>4);
    int off = (kind==0?0:kind==1?16384:kind==2?32768:kind==3?49152:53248) + f*8;
    #pragma unroll
    for (int e=0;e<8;e++){
      float v;
      int kk = 32*q + kq + e;
      if (kind==0)      v = W2L[(16*tile+m)*128 + kk];
      else if (kind==1) v = W2V[(16*tile+m)*128 + kk];
      else if (kind==2) v = W2V[kk*128 + (16*tile+m)];
      else if (kind==3){ int r = 16*tile+m; v = (r<21) ? W3L[r*128 + kk] : 0.0f; }
      else              v = (m<12) ? W1V[kk*12 + m] : 0.0f;
      _Float16 hi = (_Float16)v;
      _Float16 lo = (_Float16)(v - (float)hi);
      fragHi[off+e] = hi; fragLo[off+e] = lo;
    }
  }
  // stage-0 viol ballot (viol pre-zeroed by hipMemsetAsync)
  {
    unsigned mask = 0;
    const float* o = obs + t*12;
    #pragma unroll
    for (int i=0;i<6;i++){
      float q = o[i];
      float lo = c_LOWER[i]+0.1f, up = c_UPPER[i]-0.1f;
      if (q <= lo || q >= up) mask |= (1u<<i);
    }
    unsigned wm = 0;
    #pragma unroll
    for (int i=0;i<6;i++) if (__ballot((int)((mask>>i)&1u))) wm |= (1u<<i);
    if ((threadIdx.x & 63)==0 && wm) atomicOr(viol, (int)wm);
  }
}

// ---------------- one RK4 stage for one 16-sample tile --------------------
__device__ __forceinline__ void stage_body(int stage, int s0, SmemT& sm,
    const float* __restrict__ obs,
    float* __restrict__ q_cur, float* __restrict__ qd_cur,
    const float* __restrict__ action,
    const float* __restrict__ W1LT, const float* __restrict__ b1L,
    const float* __restrict__ b2L,  const float* __restrict__ b3Lp,
    const float* __restrict__ W1VT, const float* __restrict__ b1V,
    const float* __restrict__ b2V,  const float* __restrict__ W3V,
    const float* __restrict__ W1V,
    const _Float16* __restrict__ fragHi, const _Float16* __restrict__ fragLo,
    int* __restrict__ viol, float* __restrict__ kqd, float* __restrict__ out)
{
  auto Bact = reinterpret_cast<_Float16 (*)[16][136]>(sm.u);  // [2][16][136]
  auto dyp  = reinterpret_cast<float (*)[17]>(sm.u);          // [42][17]
  auto dvp  = reinterpret_cast<float (*)[17]>(sm.u);          // [12][17]

  const int tid = threadIdx.x;
  const int l = tid & 63;
  const int w = tid >> 6;
  const int lane_n = l & 15;
  const int quad = l >> 4;
  const int base0 = w*16 + quad*4;
  const int base1 = (w+4)*16 + quad*4;
  const int vm = __hip_atomic_load(viol + stage, __ATOMIC_RELAXED, __HIP_MEMORY_SCOPE_AGENT);

  const half8_t* fW2Lh  = (const half8_t*)(fragHi);
  const half8_t* fW2Ll  = (const half8_t*)(fragLo);
  const half8_t* fW2Vh  = (const half8_t*)(fragHi + 16384);
  const half8_t* fW2Vl  = (const half8_t*)(fragLo + 16384);
  const half8_t* fW2VTh = (const half8_t*)(fragHi + 32768);
  const half8_t* fW2VTl = (const half8_t*)(fragLo + 32768);
  const half8_t* fW3h   = (const half8_t*)(fragHi + 49152);
  const half8_t* fW3l   = (const half8_t*)(fragLo + 49152);
  const half8_t* fW1Th  = (const half8_t*)(fragHi + 53248);
  const half8_t* fW1Tl  = (const half8_t*)(fragLo + 53248);

  __syncthreads();   // tile-loop hazard: prior tile's readers vs phase-0 writes

  // ---- phase 0: trig, tau, constraint force
  if (tid < 96){
    int s = tid & 15, i = tid >> 4;
    float q, qdv;
    if (stage == 0){ q = obs[(s0+s)*12 + i]; qdv = obs[(s0+s)*12 + 6 + i]; }
    else           { q = q_cur[(s0+s)*6 + i]; qdv = qd_cur[(s0+s)*6 + i]; }
    sm.qd[i][s] = qdv;
    sm.tau[i][s] = action[(s0+s)*6+i] * c_EFFORT[i];
    el(sm.t, 2*i,   s) = cosf(q);
    el(sm.t, 2*i+1, s) = sinf(q);
    float lo = c_LOWER[i]+0.1f, up = c_UPPER[i]-0.1f;
    float barrier = -5.0f*(1.0f/(q-lo) - 1.0f/(up-q));
    float clip = (q<=lo)? c_EFFORT[i] : ((q>=up)? -c_EFFORT[i] : 0.0f);
    sm.f[i][s] = ((vm>>i)&1) ? clip : barrier;
    sm.c[i][s] = 0.0f;
  }
  __syncthreads();

  float4 s1a, s1b;
  // ---- L1L (VALU) -> Bact
  {
    float2 bb = *reinterpret_cast<const float2*>(b1L + 2*l);
    float4 z0 = f4all(bb.x), z1 = f4all(bb.y);
    #pragma unroll
    for (int i=0;i<12;i++){
      float2 wv = *reinterpret_cast<const float2*>(W1LT + i*128 + 2*l);
      float4 a = *chunkc(sm.t, i, w);
      fma4(z0, wv.x, a); fma4(z1, wv.y, a);
    }
    float4 h0 = sp4(z0), h1 = sp4(z1);
    s1a = sig4(z0); s1b = sig4(z1);
    #pragma unroll
    for (int j=0;j<4;j++)
      stB2(Bact[0], Bact[1], 4*w+j, 2*l, (&h0.x)[j], (&h1.x)[j]);
  }
  __syncthreads();

  float4 s2a, s2b;
  // ---- L2L MFMA + epilogue (h2 -> Bact in-place)
  {
    f32x4 acc0 = {0.f,0.f,0.f,0.f}, acc1 = {0.f,0.f,0.f,0.f};
    #pragma unroll
    for (int q=0;q<4;q++){
      half8_t bh = ldB(Bact[0], lane_n, q, quad);
      half8_t bl = ldB(Bact[1], lane_n, q, quad);
      acc0 = mfma3(fW2Lh[(w*4+q)*64+l],     fW2Ll[(w*4+q)*64+l],     bh, bl, acc0);
      acc1 = mfma3(fW2Lh[((w+4)*4+q)*64+l], fW2Ll[((w+4)*4+q)*64+l], bh, bl, acc1);
    }
    __syncthreads();
    float4 ba = *reinterpret_cast<const float4*>(b2L + base0);
    float4 bb = *reinterpret_cast<const float4*>(b2L + base1);
    float4 h2a, h2b;
    #pragma unroll
    for (int j=0;j<4;j++){
      float z = acc0[j] + (&ba.x)[j];
      (&h2a.x)[j] = sp_f(z); (&s2a.x)[j] = sig_f(z);
      z = acc1[j] + (&bb.x)[j];
      (&h2b.x)[j] = sp_f(z); (&s2b.x)[j] = sig_f(z);
    }
    stB4(Bact[0], Bact[1], lane_n, base0, h2a);
    stB4(Bact[0], Bact[1], lane_n, base1, h2b);
  }
  __syncthreads();

  // ---- L3 MFMA (waves 0,1) -> y only (s3 via identity later)
  if (w < 2){
    f32x4 acc = {0.f,0.f,0.f,0.f};
    #pragma unroll
    for (int q=0;q<4;q++){
      half8_t bh = ldB(Bact[0], lane_n, q, quad);
      half8_t bl = ldB(Bact[1], lane_n, q, quad);
      acc = mfma3(fW3h[(w*4+q)*64+l], fW3l[(w*4+q)*64+l], bh, bl, acc);
    }
    int rb = w*16 + quad*4;
    #pragma unroll
    for (int j=0;j<4;j++){
      int r = rb + j;
      if (r < 21) sm.y[r][lane_n] = sp_f(acc[j] + b3Lp[r]);
    }
  }
  __syncthreads();

  // ---- v = L^T qdot
  if (tid < 96){
    int s = tid & 15, jj = tid >> 4;
    float acc = 0.f;
    for (int i=jj;i<6;i++) acc = fmaf(sm.y[c_ROWOFF[i]+jj][s], sm.qd[i][s], acc);
    sm.v[jj][s] = acc;
  }

  // ---- tangent groups: dirs {2G, 2G+1}
  for (int G=0; G<3; ++G){
    #pragma unroll
    for (int d=0; d<2; ++d){
      int g = 2*G + d;
      float2 w0 = *reinterpret_cast<const float2*>(W1LT + (2*g)*128 + 2*l);
      float2 w1 = *reinterpret_cast<const float2*>(W1LT + (2*g+1)*128 + 2*l);
      float4 tc = *chunkc(sm.t, 2*g,   w);
      float4 ts = *chunkc(sm.t, 2*g+1, w);
      #pragma unroll
      for (int j=0;j<4;j++){
        float tcj = (&tc.x)[j], tsj = (&ts.x)[j];
        float d0 = (&s1a.x)[j]*(tcj*w1.x - tsj*w0.x);
        float d1 = (&s1b.x)[j]*(tcj*w1.y - tsj*w0.y);
        stB2(sm.Bd[d][0], sm.Bd[d][1], 4*w+j, 2*l, d0, d1);
      }
    }
    __syncthreads();
    f32x4 ta00={0.f,0.f,0.f,0.f}, ta01=ta00, ta10=ta00, ta11=ta00;
    #pragma unroll
    for (int q=0;q<4;q++){
      half8_t b0h = ldB(sm.Bd[0][0], lane_n, q, quad);
      half8_t b0l = ldB(sm.Bd[0][1], lane_n, q, quad);
      half8_t b1h = ldB(sm.Bd[1][0], lane_n, q, quad);
      half8_t b1l = ldB(sm.Bd[1][1], lane_n, q, quad);
      half8_t a0h = fW2Lh[(w*4+q)*64+l],     a0l = fW2Ll[(w*4+q)*64+l];
      half8_t a1h = fW2Lh[((w+4)*4+q)*64+l], a1l = fW2Ll[((w+4)*4+q)*64+l];
      ta00 = mfma3(a0h, a0l, b0h, b0l, ta00);
      ta01 = mfma3(a0h, a0l, b1h, b1l, ta01);
      ta10 = mfma3(a1h, a1l, b0h, b0l, ta10);
      ta11 = mfma3(a1h, a1l, b1h, b1l, ta11);
    }
    __syncthreads();
    {
      float4 v;
      #pragma unroll
      for (int j=0;j<4;j++) (&v.x)[j] = (&s2a.x)[j]*ta00[j];
      stB4(sm.Bd[0][0], sm.Bd[0][1], lane_n, base0, v);
      #pragma unroll
      for (int j=0;j<4;j++) (&v.x)[j] = (&s2b.x)[j]*ta10[j];
      stB4(sm.Bd[0][0], sm.Bd[0][1], lane_n, base1, v);
      #pragma unroll
      for (int j=0;j<4;j++) (&v.x)[j] = (&s2a.x)[j]*ta01[j];
      stB4(sm.Bd[1][0], sm.Bd[1][1], lane_n, base0, v);
      #pragma unroll
      for (int j=0;j<4;j++) (&v.x)[j] = (&s2b.x)[j]*ta11[j];
      stB4(sm.Bd[1][0], sm.Bd[1][1], lane_n, base1, v);
    }
    __syncthreads();
    {
      int d = w & 1, tt = w >> 1;
      f32x4 acc = {0.f,0.f,0.f,0.f};
      #pragma unroll
      for (int q=0;q<4;q++){
        half8_t bh = ldB(sm.Bd[d][0], lane_n, q, quad);
        half8_t bl = ldB(sm.Bd[d][1], lane_n, q, quad);
        acc = mfma3(fW3h[(tt*4+q)*64+l], fW3l[(tt*4+q)*64+l], bh, bl, acc);
      }
      int rb = tt*16 + quad*4;
      #pragma unroll
      for (int j=0;j<4;j++){
        int r = rb + j;
        if (r < 21){
          float s3 = 1.0f - __expf(-sm.y[r][lane_n]);   // sig(z)=1-exp(-sp(z))
          dyp[d*21 + r][lane_n] = s3 * acc[j];
        }
      }
    }
    __syncthreads();
    if (tid < 32){
      int s = tid & 15, gg = tid >> 4;
      float qd[6];
      #pragma unroll
      for (int i=0;i<6;i++) qd[i] = sm.qd[i][s];
      float u[6];
      #pragma unroll
      for (int jj=0;jj<6;jj++){
        float acc = 0.f;
        for (int i=jj;i<6;i++) acc = fmaf(dyp[gg*21 + c_ROWOFF[i]+jj][s], qd[i], acc);
        u[jj] = acc;
      }
      #pragma unroll
      for (int i=0;i<6;i++){
        float acc = 0.f;
        for (int j=0;j<=i;j++){
          acc = fmaf(dyp[gg*21 + c_ROWOFF[i]+j][s], sm.v[j][s], acc);
          acc = fmaf(sm.y[c_ROWOFF[i]+j][s], u[j], acc);
        }
        sm.wg[gg][i][s] = acc;
      }
    }
    __syncthreads();
    if (tid < 96){
      int s = tid & 15, i = tid >> 4;
      float acc = sm.c[i][s];
      acc = fmaf(sm.qd[2*G][s],   sm.wg[0][i][s], acc);
      acc = fmaf(sm.qd[2*G+1][s], sm.wg[1][i][s], acc);
      int gi = i - 2*G;
      if (gi == 0 || gi == 1){
        float r = 0.f;
        #pragma unroll
        for (int j=0;j<6;j++) r = fmaf(sm.qd[j][s], sm.wg[gi][j][s], r);
        acc -= 0.5f*r;
      }
      sm.c[i][s] = acc;
    }
    __syncthreads();
  }

  // ---- V-net L1 (VALU) -> Bact (dy dead)
  {
    float2 bb = *reinterpret_cast<const float2*>(b1V + 2*l);
    float4 z0 = f4all(bb.x), z1 = f4all(bb.y);
    #pragma unroll
    for (int i=0;i<12;i++){
      float2 wv = *reinterpret_cast<const float2*>(W1VT + i*128 + 2*l);
      float4 a = *chunkc(sm.t, i, w);
      fma4(z0, wv.x, a); fma4(z1, wv.y, a);
    }
    float4 h0 = sp4(z0), h1 = sp4(z1);
    #pragma unroll
    for (int j=0;j<4;j++)
      stB2(Bact[0], Bact[1], 4*w+j, 2*l, (&h0.x)[j], (&h1.x)[j]);
  }
  __syncthreads();
  // ---- L2V MFMA; epilogue g2 = sig(z)*W3V -> Bact in-place
  {
    f32x4 acc0 = {0.f,0.f,0.f,0.f}, acc1 = {0.f,0.f,0.f,0.f};
    #pragma unroll
    for (int q=0;q<4;q++){
      half8_t bh = ldB(Bact[0], lane_n, q, quad);
      half8_t bl = ldB(Bact[1], lane_n, q, quad);
      acc0 = mfma3(fW2Vh[(w*4+q)*64+l],     fW2Vl[(w*4+q)*64+l],     bh, bl, acc0);
      acc1 = mfma3(fW2Vh[((w+4)*4+q)*64+l], fW2Vl[((w+4)*4+q)*64+l], bh, bl, acc1);
    }
    __syncthreads();
    float4 ba  = *reinterpret_cast<const float4*>(b2V + base0);
    float4 bb  = *reinterpret_cast<const float4*>(b2V + base1);
    float4 w3a = *reinterpret_cast<const float4*>(W3V + base0);
    float4 w3b = *reinterpret_cast<const float4*>(W3V + base1);
    float4 g2a, g2b;
    #pragma unroll
    for (int j=0;j<4;j++){
      (&g2a.x)[j] = sig_f(acc0[j] + (&ba.x)[j]) * (&w3a.x)[j];
      (&g2b.x)[j] = sig_f(acc1[j] + (&bb.x)[j]) * (&w3b.x)[j];
    }
    stB4(Bact[0], Bact[1], lane_n, base0, g2a);
    stB4(Bact[0], Bact[1], lane_n, base1, g2b);
  }
  __syncthreads();
  // ---- V bwd MFMA (A = W2V^T); epilogue: recompute s1V, g1 -> Bd[0]
  {
    f32x4 acc0 = {0.f,0.f,0.f,0.f}, acc1 = {0.f,0.f,0.f,0.f};
    #pragma unroll
    for (int q=0;q<4;q++){
      half8_t bh = ldB(Bact[0], lane_n, q, quad);
      half8_t bl = ldB(Bact[1], lane_n, q, quad);
      acc0 = mfma3(fW2VTh[(w*4+q)*64+l],     fW2VTl[(w*4+q)*64+l],     bh, bl, acc0);
      acc1 = mfma3(fW2VTh[((w+4)*4+q)*64+l], fW2VTl[((w+4)*4+q)*64+l], bh, bl, acc1);
    }
    float tn[12];
    #pragma unroll
    for (int i=0;i<12;i++) tn[i] = el(sm.t, i, lane_n);
    float4 g1a, g1b;
    #pragma unroll
    for (int j=0;j<4;j++){
      int r = base0 + j;
      float z = b1V[r];
      const float* wr = W1V + r*12;
      #pragma unroll
      for (int i=0;i<12;i++) z = fmaf(wr[i], tn[i], z);
      (&g1a.x)[j] = sig_f(z) * acc0[j];
      r = base1 + j;
      z = b1V[r];
      wr = W1V + r*12;
      #pragma unroll
      for (int i=0;i<12;i++) z = fmaf(wr[i], tn[i], z);
      (&g1b.x)[j] = sig_f(z) * acc1[j];
    }
    stB4(sm.Bd[0][0], sm.Bd[0][1], lane_n, base0, g1a);
    stB4(sm.Bd[0][0], sm.Bd[0][1], lane_n, base1, g1b);
  }
  __syncthreads();
  // ---- dV/dt = W1V^T g1 via MFMA (wave 0; Bact dead -> dv overlay)
  if (w == 0){
    f32x4 acc = {0.f,0.f,0.f,0.f};
    #pragma unroll
    for (int q=0;q<4;q++){
      half8_t bh = ldB(sm.Bd[0][0], lane_n, q, quad);
      half8_t bl = ldB(sm.Bd[0][1], lane_n, q, quad);
      acc = mfma3(fW1Th[q*64+l], fW1Tl[q*64+l], bh, bl, acc);
    }
    int rb = quad*4;
    #pragma unroll
    for (int j=0;j<4;j++){
      int r = rb + j;
      if (r < 12) dvp[r][lane_n] = acc[j];
    }
  }
  __syncthreads();
  // ---- gravity
  if (tid < 96){
    int k = tid>>4, s = tid&15;
    sm.grav[k][s] = fmaf(el(sm.t,2*k,s), dvp[2*k+1][s],
                         -(el(sm.t,2*k+1,s)*dvp[2*k][s]));
  }
  __syncthreads();
  // ---- assembly + triangular solves + folded pre / final combine
  if (l < 4){
    int s = w*4 + l;
    float Lm[21];
    #pragma unroll
    for (int o=0;o<21;o++) Lm[o] = sm.y[o][s];
    float rhs[6];
    #pragma unroll
    for (int i=0;i<6;i++) rhs[i] = sm.tau[i][s] - sm.c[i][s] - sm.grav[i][s] - sm.f[i][s];
    float z[6];
    #pragma unroll
    for (int i=0;i<6;i++){
      float acc = rhs[i];
      for (int j=0;j<i;j++) acc = fmaf(-Lm[c_ROWOFF[i]+j], z[j], acc);
      z[i] = acc * __builtin_amdgcn_rcpf(Lm[c_ROWOFF[i]+i]);
    }
    float a[6];
    #pragma unroll
    for (int i=5;i>=0;i--){
      float acc = z[i];
      for (int j=i+1;j<6;j++) acc = fmaf(-Lm[c_ROWOFF[j]+i], a[j], acc);
      a[i] = acc * __builtin_amdgcn_rcpf(Lm[c_ROWOFF[i]+i]);
    }
    int b = s0 + s;
    const float* o = obs + b*12;
    if (stage < 3){
      float* kqd_out = kqd + stage*B6;
      #pragma unroll
      for (int i=0;i<6;i++) kqd_out[b*6+i] = a[i];
      unsigned mask = 0;
      #pragma unroll
      for (int i=0;i<6;i++){
        float q0=o[i], qd0=o[6+i];
        float q, qd;
        if (stage == 0){
          q  = q0 + 0.5f*DT*qd0;
          qd = qd0 + 0.5f*DT*a[i];
        } else if (stage == 1){
          float k1 = kqd[b*6+i];
          q  = q0 + 0.5f*DT*qd0 + 0.25f*DT*DT*k1;
          qd = qd0 + 0.5f*DT*a[i];
        } else {
          float k2 = kqd[B6 + b*6+i];
          q  = q0 + DT*qd0 + 0.5f*DT*DT*k2;
          qd = qd0 + DT*a[i];
        }
        q_cur[b*6+i]=q; qd_cur[b*6+i]=qd;
        float lo = c_LOWER[i]+0.1f, up = c_UPPER[i]-0.1f;
        if (q <= lo || q >= up) mask |= (1u<<i);
      }
      if (mask) atomicOr(viol + stage + 1, (int)mask);
    } else {
      // final RK4 combine: a == k4
      #pragma unroll
      for (int i=0;i<6;i++){
        float q0=o[i], qd0=o[6+i];
        float k1=kqd[b*6+i], k2=kqd[B6+b*6+i], k3=kqd[2*B6+b*6+i];
        float qn = q0 + DT*qd0 + (DT*DT/6.0f)*(k1+k2+k3);
        qn = fminf(fmaxf(qn, c_LOWER[i]), c_UPPER[i]);
        out[b*12+i] = qn;
        out[b*12+6+i] = qd0 + (DT/6.0f)*(k1 + 2.0f*k2 + 2.0f*k3 + a[i]);
      }
    }
  }
}

// ---------------- unified stage kernel (grid-strided over tiles) ----------
// NOTE: plain __launch_bounds__(256) — the ",4" min-waves hint caused 64-VGPR
// pinning + 1.5 GB of scratch spill traffic in r9. Never re-add it.
__global__ void __launch_bounds__(256) k_stages(
    int s_begin, int s_end,
    const float* __restrict__ obs,
    float* __restrict__ q_cur, float* __restrict__ qd_cur,
    const float* __restrict__ action,
    const float* __restrict__ W1LT, const float* __restrict__ b1L,
    const float* __restrict__ b2L,  const float* __restrict__ b3Lp,
    const float* __restrict__ W1VT, const float* __restrict__ b1V,
    const float* __restrict__ b2V,  const float* __restrict__ W3V,
    const float* __restrict__ W1V,
    const _Float16* __restrict__ fragHi, const _Float16* __restrict__ fragLo,
    int* __restrict__ viol, float* __restrict__ kqd, float* __restrict__ out)
{
  __shared__ SmemT sm;
  for (int s = s_begin; s < s_end; ++s){
    for (int tile = blockIdx.x; tile < NTILES; tile += gridDim.x){
      stage_body(s, tile*16, sm, obs, q_cur, qd_cur, action,
                 W1LT, b1L, b2L, b3Lp, W1VT, b1V, b2V, W3V, W1V,
                 fragHi, fragLo, viol, kqd, out);
    }
    if (s + 1 < s_end){
      cg::this_grid().sync();
    }
  }
}

extern "C" void kernel_launch(void* const* d_in, const int* in_sizes, int n_in,
                              void* d_out, int out_size, void* d_ws, size_t ws_size,
                              hipStream_t stream) {
  const float* obs    = (const float*)d_in[0];
  const float* action = (const float*)d_in[1];
  const float* W1L = (const float*)d_in[2];  const float* b1L = (const float*)d_in[3];
  const float* W2L = (const float*)d_in[4];  const float* b2L = (const float*)d_in[5];
  const float* W3L = (const float*)d_in[6];  const float* b3L = (const float*)d_in[7];
  const float* W1V = (const float*)d_in[8];  const float* b1V = (const float*)d_in[9];
  const float* W2V = (const float*)d_in[10]; const float* b2V = (const float*)d_in[11];
  const float* W3V = (const float*)d_in[12]; // b3V unused: only grad of V needed

  float* ws = (float*)d_ws;
  _Float16* fragHi = (_Float16*)ws;            // 55296 halves
  _Float16* fragLo = fragHi + 55296;           // 55296 halves
  float* W1LT  = ws + 55296;                   // 1536
  float* W1VT  = W1LT + 1536;                  // 1536
  float* b3Lp  = W1VT + 1536;                  // 32
  float* q_cur  = b3Lp + 32;                   // B6
  float* qd_cur = q_cur + B6;                  // B6
  float* kqd    = qd_cur + B6;                 // 3*B6
  int*   viol   = (int*)(kqd + 3*B6);          // 4

  float* out = (float*)d_out;

  hipMemsetAsync(viol, 0, 16, stream);
  k_init<<<64,256,0,stream>>>(obs, W1L, W2L, W3L, W1V, W2V, b3L,
                              W1LT, W1VT, b3Lp, fragHi, fragLo, viol);

  // Co-residency check (host-side, deterministic, capture-safe)
  int maxBpCU = 0;
  hipError_t qerr = hipOccupancyMaxActiveBlocksPerMultiprocessor(&maxBpCU, k_stages, 256, 0);
  bool coop_ok = (qerr == hipSuccess && maxBpCU >= 4);

  if (coop_ok){
    int sb = 0, se = 4;
    void* args[] = {
      (void*)&sb, (void*)&se,
      (void*)&obs, (void*)&q_cur, (void*)&qd_cur, (void*)&action,
      (void*)&W1LT, (void*)&b1L, (void*)&b2L, (void*)&b3Lp,
      (void*)&W1VT, (void*)&b1V, (void*)&b2V, (void*)&W3V, (void*)&W1V,
      (void*)&fragHi, (void*)&fragLo,
      (void*)&viol, (void*)&kqd, (void*)&out
    };
    hipError_t err = hipLaunchCooperativeKernel((const void*)k_stages,
                                                dim3(NTILES), dim3(256),
                                                args, 0, stream);
    if (err == hipSuccess) return;
    (void)hipGetLastError();  // clear sticky error, fall through
  }
  for (int s = 0; s < 4; ++s){
    k_stages<<<NTILES,256,0,stream>>>(s, s+1, obs, q_cur, qd_cur, action,
        W1LT, b1L, b2L, b3Lp, W1VT, b1V, b2V, W3V, W1V,
        fragHi, fragLo, viol, kqd, out);
  }
}

// Round 11
// 275.580 us; speedup vs baseline: 4.2518x; 3.5324x over previous
//
#include <hip/hip_runtime.h>
#include <math.h>

#define BATCH 16384
#define B6 (BATCH*6)
#define DT 0.01f

using half8_t = __attribute__((ext_vector_type(8))) _Float16;
using half4_t = __attribute__((ext_vector_type(4))) _Float16;
using half2_t = __attribute__((ext_vector_type(2))) _Float16;
using f32x4   = __attribute__((ext_vector_type(4))) float;

__device__ __constant__ float c_LOWER[6]  = {-6.28f,-6.28f,-3.14f,-6.28f,-6.28f,-6.28f};
__device__ __constant__ float c_UPPER[6]  = { 6.28f, 6.28f, 3.14f, 6.28f, 6.28f, 6.28f};
__device__ __constant__ float c_EFFORT[6] = {150.0f,150.0f,150.0f,28.0f,28.0f,28.0f};
__device__ __constant__ int   c_ROWOFF[6] = {0,1,3,6,10,15};

__device__ __forceinline__ float sp_f(float z){
  return fmaxf(z,0.0f) + __logf(1.0f + __expf(-fabsf(z)));
}
__device__ __forceinline__ float sig_f(float z){
  return __builtin_amdgcn_rcpf(1.0f + __expf(-z));
}

__device__ __forceinline__ float4 f4all(float v){ return make_float4(v,v,v,v); }
__device__ __forceinline__ void fma4(float4& acc, float w, float4 a){
  acc.x=fmaf(w,a.x,acc.x); acc.y=fmaf(w,a.y,acc.y); acc.z=fmaf(w,a.z,acc.z); acc.w=fmaf(w,a.w,acc.w);
}
__device__ __forceinline__ float4 sp4(float4 z){
  return make_float4(sp_f(z.x),sp_f(z.y),sp_f(z.z),sp_f(z.w));
}
__device__ __forceinline__ float4 sig4(float4 z){
  return make_float4(sig_f(z.x),sig_f(z.y),sig_f(z.z),sig_f(z.w));
}

// XOR-swizzled accessors for sh_t [12][16] (r3/r4-verified conflict-free)
__device__ __forceinline__ const float4* chunkc(const float (*arr)[16], int n, int cc){
  return reinterpret_cast<const float4*>(&arr[n][4*(cc ^ ((n>>1)&3))]);
}
__device__ __forceinline__ float& el(float (*arr)[16], int n, int s){
  return arr[n][4*((s>>2) ^ ((n>>1)&3)) + (s&3)];
}

// ---- MFMA helpers --------------------------------------------------------
__device__ __forceinline__ f32x4 mfma3(half8_t ah, half8_t al, half8_t bh, half8_t bl, f32x4 acc){
  acc = __builtin_amdgcn_mfma_f32_16x16x32_f16(ah, bh, acc, 0,0,0);
  acc = __builtin_amdgcn_mfma_f32_16x16x32_f16(ah, bl, acc, 0,0,0);
  acc = __builtin_amdgcn_mfma_f32_16x16x32_f16(al, bh, acc, 0,0,0);
  return acc;
}
__device__ __forceinline__ half8_t ldB(const _Float16 (*B)[136], int n, int q, int quad){
  return *reinterpret_cast<const half8_t*>(&B[n][q*32 + quad*8]);
}
__device__ __forceinline__ void stB4(_Float16 (*Bh)[136], _Float16 (*Bl)[136], int n, int base, float4 v){
  half4_t hi, lo;
  const float* p = &v.x;
  #pragma unroll
  for (int j=0;j<4;j++){ hi[j] = (_Float16)p[j]; lo[j] = (_Float16)(p[j] - (float)hi[j]); }
  *reinterpret_cast<half4_t*>(&Bh[n][base]) = hi;
  *reinterpret_cast<half4_t*>(&Bl[n][base]) = lo;
}
__device__ __forceinline__ void stB2(_Float16 (*Bh)[136], _Float16 (*Bl)[136], int n, int k2, float a, float b){
  half2_t hi, lo;
  hi[0]=(_Float16)a; hi[1]=(_Float16)b;
  lo[0]=(_Float16)(a-(float)hi[0]); lo[1]=(_Float16)(b-(float)hi[1]);
  *reinterpret_cast<half2_t*>(&Bh[n][k2]) = hi;
  *reinterpret_cast<half2_t*>(&Bl[n][k2]) = lo;
}

// ---- shared-memory layout (union'd regions, ~31.4 KB) --------------------
struct SmemT {
  alignas(16) char u[8704];                 // Bact[2][16][136] | dy[42][17] | dv[12][17]
  alignas(16) _Float16 Bd[2][2][16][136];
  alignas(16) float t[12][16];
  float y[21][17];
  float wg[2][6][16];
  float qd[6][16], tau[6][16], f[6][16];
  float c[6][16], grav[6][16], v[6][16];
};

// ---------------- init: transposes + split-fp16 A-fragments + stage-0 viol
__global__ void __launch_bounds__(256) k_init(
    const float* __restrict__ obs,
    const float* __restrict__ W1L, const float* __restrict__ W2L,
    const float* __restrict__ W3L, const float* __restrict__ W1V,
    const float* __restrict__ W2V, const float* __restrict__ b3L,
    float* __restrict__ W1LT, float* __restrict__ W1VT, float* __restrict__ b3Lp,
    _Float16* __restrict__ fragHi, _Float16* __restrict__ fragLo, int* __restrict__ viol)
{
  int t = blockIdx.x*256 + threadIdx.x;
  if (t < 1536){ int i = t/128, k = t%128; W1LT[t] = W1L[k*12+i]; W1VT[t] = W1V[k*12+i]; }
  if (t < 32) b3Lp[t] = (t < 21) ? b3L[t] : 0.0f;
  if (t < 6912){
    int kind, f;
    if (t < 2048){ kind=0; f=t; }
    else if (t < 4096){ kind=1; f=t-2048; }
    else if (t < 6144){ kind=2; f=t-4096; }
    else if (t < 6656){ kind=3; f=t-6144; }
    else { kind=4; f=t-6656; }
    int tile = f>>8, q = (f>>6)&3, l = f&63, m = l&15, kq = 8*(l>>4);
    int off = (kind==0?0:kind==1?16384:kind==2?32768:kind==3?49152:53248) + f*8;
    #pragma unroll
    for (int e=0;e<8;e++){
      float v;
      int kk = 32*q + kq + e;
      if (kind==0)      v = W2L[(16*tile+m)*128 + kk];
      else if (kind==1) v = W2V[(16*tile+m)*128 + kk];
      else if (kind==2) v = W2V[kk*128 + (16*tile+m)];
      else if (kind==3){ int r = 16*tile+m; v = (r<21) ? W3L[r*128 + kk] : 0.0f; }
      else              v = (m<12) ? W1V[kk*12 + m] : 0.0f;
      _Float16 hi = (_Float16)v;
      _Float16 lo = (_Float16)(v - (float)hi);
      fragHi[off+e] = hi; fragLo[off+e] = lo;
    }
  }
  // stage-0 viol ballot (viol pre-zeroed by hipMemsetAsync)
  {
    unsigned mask = 0;
    const float* o = obs + t*12;
    #pragma unroll
    for (int i=0;i<6;i++){
      float q = o[i];
      float lo = c_LOWER[i]+0.1f, up = c_UPPER[i]-0.1f;
      if (q <= lo || q >= up) mask |= (1u<<i);
    }
    unsigned wm = 0;
    #pragma unroll
    for (int i=0;i<6;i++) if (__ballot((int)((mask>>i)&1u))) wm |= (1u<<i);
    if ((threadIdx.x & 63)==0 && wm) atomicOr(viol, (int)wm);
  }
}

// ---------------- per-stage accel kernel ----------------
// NOTE (learned r3/r9/r10): NO __launch_bounds__ min-waves hint and NO outer
// loops around this body — both explode VGPR use (64-pin spills / 256-VGPR
// liveness) and cost 2-4x in scratch traffic. Plain per-stage launches only.
__global__ void __launch_bounds__(256) k_accel(
    int stage,
    const float* __restrict__ obs,
    float* __restrict__ q_cur, float* __restrict__ qd_cur,
    const float* __restrict__ action,
    const float* __restrict__ W1LT, const float* __restrict__ b1L,
    const float* __restrict__ b2L,  const float* __restrict__ b3Lp,
    const float* __restrict__ W1VT, const float* __restrict__ b1V,
    const float* __restrict__ b2V,  const float* __restrict__ W3V,
    const float* __restrict__ W1V,
    const _Float16* __restrict__ fragHi, const _Float16* __restrict__ fragLo,
    int* __restrict__ viol, float* __restrict__ kqd, float* __restrict__ out)
{
  __shared__ SmemT sm;
  auto Bact = reinterpret_cast<_Float16 (*)[16][136]>(sm.u);  // [2][16][136]
  auto dyp  = reinterpret_cast<float (*)[17]>(sm.u);          // [42][17]
  auto dvp  = reinterpret_cast<float (*)[17]>(sm.u);          // [12][17]

  const int tid = threadIdx.x;
  const int l = tid & 63;
  const int w = tid >> 6;
  const int lane_n = l & 15;
  const int quad = l >> 4;
  const int base0 = w*16 + quad*4;
  const int base1 = (w+4)*16 + quad*4;
  const int s0 = blockIdx.x * 16;
  const int vm = __hip_atomic_load(viol + stage, __ATOMIC_RELAXED, __HIP_MEMORY_SCOPE_AGENT);

  const half8_t* fW2Lh  = (const half8_t*)(fragHi);
  const half8_t* fW2Ll  = (const half8_t*)(fragLo);
  const half8_t* fW2Vh  = (const half8_t*)(fragHi + 16384);
  const half8_t* fW2Vl  = (const half8_t*)(fragLo + 16384);
  const half8_t* fW2VTh = (const half8_t*)(fragHi + 32768);
  const half8_t* fW2VTl = (const half8_t*)(fragLo + 32768);
  const half8_t* fW3h   = (const half8_t*)(fragHi + 49152);
  const half8_t* fW3l   = (const half8_t*)(fragLo + 49152);
  const half8_t* fW1Th  = (const half8_t*)(fragHi + 53248);
  const half8_t* fW1Tl  = (const half8_t*)(fragLo + 53248);

  // ---- phase 0: trig, tau, constraint force
  if (tid < 96){
    int s = tid & 15, i = tid >> 4;
    float q, qdv;
    if (stage == 0){ q = obs[(s0+s)*12 + i]; qdv = obs[(s0+s)*12 + 6 + i]; }
    else           { q = q_cur[(s0+s)*6 + i]; qdv = qd_cur[(s0+s)*6 + i]; }
    sm.qd[i][s] = qdv;
    sm.tau[i][s] = action[(s0+s)*6+i] * c_EFFORT[i];
    el(sm.t, 2*i,   s) = cosf(q);
    el(sm.t, 2*i+1, s) = sinf(q);
    float lo = c_LOWER[i]+0.1f, up = c_UPPER[i]-0.1f;
    float barrier = -5.0f*(1.0f/(q-lo) - 1.0f/(up-q));
    float clip = (q<=lo)? c_EFFORT[i] : ((q>=up)? -c_EFFORT[i] : 0.0f);
    sm.f[i][s] = ((vm>>i)&1) ? clip : barrier;
    sm.c[i][s] = 0.0f;
  }
  __syncthreads();

  float4 s1a, s1b;
  // ---- L1L (VALU) -> Bact
  {
    float2 bb = *reinterpret_cast<const float2*>(b1L + 2*l);
    float4 z0 = f4all(bb.x), z1 = f4all(bb.y);
    #pragma unroll
    for (int i=0;i<12;i++){
      float2 wv = *reinterpret_cast<const float2*>(W1LT + i*128 + 2*l);
      float4 a = *chunkc(sm.t, i, w);
      fma4(z0, wv.x, a); fma4(z1, wv.y, a);
    }
    float4 h0 = sp4(z0), h1 = sp4(z1);
    s1a = sig4(z0); s1b = sig4(z1);
    #pragma unroll
    for (int j=0;j<4;j++)
      stB2(Bact[0], Bact[1], 4*w+j, 2*l, (&h0.x)[j], (&h1.x)[j]);
  }
  __syncthreads();

  float4 s2a, s2b;
  // ---- L2L MFMA + epilogue (h2 -> Bact in-place)
  {
    f32x4 acc0 = {0.f,0.f,0.f,0.f}, acc1 = {0.f,0.f,0.f,0.f};
    #pragma unroll
    for (int q=0;q<4;q++){
      half8_t bh = ldB(Bact[0], lane_n, q, quad);
      half8_t bl = ldB(Bact[1], lane_n, q, quad);
      acc0 = mfma3(fW2Lh[(w*4+q)*64+l],     fW2Ll[(w*4+q)*64+l],     bh, bl, acc0);
      acc1 = mfma3(fW2Lh[((w+4)*4+q)*64+l], fW2Ll[((w+4)*4+q)*64+l], bh, bl, acc1);
    }
    __syncthreads();
    float4 ba = *reinterpret_cast<const float4*>(b2L + base0);
    float4 bb = *reinterpret_cast<const float4*>(b2L + base1);
    float4 h2a, h2b;
    #pragma unroll
    for (int j=0;j<4;j++){
      float z = acc0[j] + (&ba.x)[j];
      (&h2a.x)[j] = sp_f(z); (&s2a.x)[j] = sig_f(z);
      z = acc1[j] + (&bb.x)[j];
      (&h2b.x)[j] = sp_f(z); (&s2b.x)[j] = sig_f(z);
    }
    stB4(Bact[0], Bact[1], lane_n, base0, h2a);
    stB4(Bact[0], Bact[1], lane_n, base1, h2b);
  }
  __syncthreads();

  // ---- L3 MFMA (waves 0,1) -> y only (s3 via identity later)
  if (w < 2){
    f32x4 acc = {0.f,0.f,0.f,0.f};
    #pragma unroll
    for (int q=0;q<4;q++){
      half8_t bh = ldB(Bact[0], lane_n, q, quad);
      half8_t bl = ldB(Bact[1], lane_n, q, quad);
      acc = mfma3(fW3h[(w*4+q)*64+l], fW3l[(w*4+q)*64+l], bh, bl, acc);
    }
    int rb = w*16 + quad*4;
    #pragma unroll
    for (int j=0;j<4;j++){
      int r = rb + j;
      if (r < 21) sm.y[r][lane_n] = sp_f(acc[j] + b3Lp[r]);
    }
  }
  __syncthreads();

  // ---- v = L^T qdot
  if (tid < 96){
    int s = tid & 15, jj = tid >> 4;
    float acc = 0.f;
    for (int i=jj;i<6;i++) acc = fmaf(sm.y[c_ROWOFF[i]+jj][s], sm.qd[i][s], acc);
    sm.v[jj][s] = acc;
  }

  // ---- tangent groups: dirs {2G, 2G+1}
  for (int G=0; G<3; ++G){
    #pragma unroll
    for (int d=0; d<2; ++d){
      int g = 2*G + d;
      float2 w0 = *reinterpret_cast<const float2*>(W1LT + (2*g)*128 + 2*l);
      float2 w1 = *reinterpret_cast<const float2*>(W1LT + (2*g+1)*128 + 2*l);
      float4 tc = *chunkc(sm.t, 2*g,   w);
      float4 ts = *chunkc(sm.t, 2*g+1, w);
      #pragma unroll
      for (int j=0;j<4;j++){
        float tcj = (&tc.x)[j], tsj = (&ts.x)[j];
        float d0 = (&s1a.x)[j]*(tcj*w1.x - tsj*w0.x);
        float d1 = (&s1b.x)[j]*(tcj*w1.y - tsj*w0.y);
        stB2(sm.Bd[d][0], sm.Bd[d][1], 4*w+j, 2*l, d0, d1);
      }
    }
    __syncthreads();
    f32x4 ta00={0.f,0.f,0.f,0.f}, ta01=ta00, ta10=ta00, ta11=ta00;
    #pragma unroll
    for (int q=0;q<4;q++){
      half8_t b0h = ldB(sm.Bd[0][0], lane_n, q, quad);
      half8_t b0l = ldB(sm.Bd[0][1], lane_n, q, quad);
      half8_t b1h = ldB(sm.Bd[1][0], lane_n, q, quad);
      half8_t b1l = ldB(sm.Bd[1][1], lane_n, q, quad);
      half8_t a0h = fW2Lh[(w*4+q)*64+l],     a0l = fW2Ll[(w*4+q)*64+l];
      half8_t a1h = fW2Lh[((w+4)*4+q)*64+l], a1l = fW2Ll[((w+4)*4+q)*64+l];
      ta00 = mfma3(a0h, a0l, b0h, b0l, ta00);
      ta01 = mfma3(a0h, a0l, b1h, b1l, ta01);
      ta10 = mfma3(a1h, a1l, b0h, b0l, ta10);
      ta11 = mfma3(a1h, a1l, b1h, b1l, ta11);
    }
    __syncthreads();
    {
      float4 v;
      #pragma unroll
      for (int j=0;j<4;j++) (&v.x)[j] = (&s2a.x)[j]*ta00[j];
      stB4(sm.Bd[0][0], sm.Bd[0][1], lane_n, base0, v);
      #pragma unroll
      for (int j=0;j<4;j++) (&v.x)[j] = (&s2b.x)[j]*ta10[j];
      stB4(sm.Bd[0][0], sm.Bd[0][1], lane_n, base1, v);
      #pragma unroll
      for (int j=0;j<4;j++) (&v.x)[j] = (&s2a.x)[j]*ta01[j];
      stB4(sm.Bd[1][0], sm.Bd[1][1], lane_n, base0, v);
      #pragma unroll
      for (int j=0;j<4;j++) (&v.x)[j] = (&s2b.x)[j]*ta11[j];
      stB4(sm.Bd[1][0], sm.Bd[1][1], lane_n, base1, v);
    }
    __syncthreads();
    {
      int d = w & 1, tt = w >> 1;
      f32x4 acc = {0.f,0.f,0.f,0.f};
      #pragma unroll
      for (int q=0;q<4;q++){
        half8_t bh = ldB(sm.Bd[d][0], lane_n, q, quad);
        half8_t bl = ldB(sm.Bd[d][1], lane_n, q, quad);
        acc = mfma3(fW3h[(tt*4+q)*64+l], fW3l[(tt*4+q)*64+l], bh, bl, acc);
      }
      int rb = tt*16 + quad*4;
      #pragma unroll
      for (int j=0;j<4;j++){
        int r = rb + j;
        if (r < 21){
          float s3 = 1.0f - __expf(-sm.y[r][lane_n]);   // sig(z)=1-exp(-sp(z))
          dyp[d*21 + r][lane_n] = s3 * acc[j];
        }
      }
    }
    __syncthreads();
    if (tid < 32){
      int s = tid & 15, gg = tid >> 4;
      float qd[6];
      #pragma unroll
      for (int i=0;i<6;i++) qd[i] = sm.qd[i][s];
      float u[6];
      #pragma unroll
      for (int jj=0;jj<6;jj++){
        float acc = 0.f;
        for (int i=jj;i<6;i++) acc = fmaf(dyp[gg*21 + c_ROWOFF[i]+jj][s], qd[i], acc);
        u[jj] = acc;
      }
      #pragma unroll
      for (int i=0;i<6;i++){
        float acc = 0.f;
        for (int j=0;j<=i;j++){
          acc = fmaf(dyp[gg*21 + c_ROWOFF[i]+j][s], sm.v[j][s], acc);
          acc = fmaf(sm.y[c_ROWOFF[i]+j][s], u[j], acc);
        }
        sm.wg[gg][i][s] = acc;
      }
    }
    __syncthreads();
    if (tid < 96){
      int s = tid & 15, i = tid >> 4;
      float acc = sm.c[i][s];
      acc = fmaf(sm.qd[2*G][s],   sm.wg[0][i][s], acc);
      acc = fmaf(sm.qd[2*G+1][s], sm.wg[1][i][s], acc);
      int gi = i - 2*G;
      if (gi == 0 || gi == 1){
        float r = 0.f;
        #pragma unroll
        for (int j=0;j<6;j++) r = fmaf(sm.qd[j][s], sm.wg[gi][j][s], r);
        acc -= 0.5f*r;
      }
      sm.c[i][s] = acc;
    }
    __syncthreads();
  }

  // ---- V-net L1 (VALU) -> Bact (dy dead)
  {
    float2 bb = *reinterpret_cast<const float2*>(b1V + 2*l);
    float4 z0 = f4all(bb.x), z1 = f4all(bb.y);
    #pragma unroll
    for (int i=0;i<12;i++){
      float2 wv = *reinterpret_cast<const float2*>(W1VT + i*128 + 2*l);
      float4 a = *chunkc(sm.t, i, w);
      fma4(z0, wv.x, a); fma4(z1, wv.y, a);
    }
    float4 h0 = sp4(z0), h1 = sp4(z1);
    #pragma unroll
    for (int j=0;j<4;j++)
      stB2(Bact[0], Bact[1], 4*w+j, 2*l, (&h0.x)[j], (&h1.x)[j]);
  }
  __syncthreads();
  // ---- L2V MFMA; epilogue g2 = sig(z)*W3V -> Bact in-place
  {
    f32x4 acc0 = {0.f,0.f,0.f,0.f}, acc1 = {0.f,0.f,0.f,0.f};
    #pragma unroll
    for (int q=0;q<4;q++){
      half8_t bh = ldB(Bact[0], lane_n, q, quad);
      half8_t bl = ldB(Bact[1], lane_n, q, quad);
      acc0 = mfma3(fW2Vh[(w*4+q)*64+l],     fW2Vl[(w*4+q)*64+l],     bh, bl, acc0);
      acc1 = mfma3(fW2Vh[((w+4)*4+q)*64+l], fW2Vl[((w+4)*4+q)*64+l], bh, bl, acc1);
    }
    __syncthreads();
    float4 ba  = *reinterpret_cast<const float4*>(b2V + base0);
    float4 bb  = *reinterpret_cast<const float4*>(b2V + base1);
    float4 w3a = *reinterpret_cast<const float4*>(W3V + base0);
    float4 w3b = *reinterpret_cast<const float4*>(W3V + base1);
    float4 g2a, g2b;
    #pragma unroll
    for (int j=0;j<4;j++){
      (&g2a.x)[j] = sig_f(acc0[j] + (&ba.x)[j]) * (&w3a.x)[j];
      (&g2b.x)[j] = sig_f(acc1[j] + (&bb.x)[j]) * (&w3b.x)[j];
    }
    stB4(Bact[0], Bact[1], lane_n, base0, g2a);
    stB4(Bact[0], Bact[1], lane_n, base1, g2b);
  }
  __syncthreads();
  // ---- V bwd MFMA (A = W2V^T); epilogue: recompute s1V, g1 -> Bd[0]
  {
    f32x4 acc0 = {0.f,0.f,0.f,0.f}, acc1 = {0.f,0.f,0.f,0.f};
    #pragma unroll
    for (int q=0;q<4;q++){
      half8_t bh = ldB(Bact[0], lane_n, q, quad);
      half8_t bl = ldB(Bact[1], lane_n, q, quad);
      acc0 = mfma3(fW2VTh[(w*4+q)*64+l],     fW2VTl[(w*4+q)*64+l],     bh, bl, acc0);
      acc1 = mfma3(fW2VTh[((w+4)*4+q)*64+l], fW2VTl[((w+4)*4+q)*64+l], bh, bl, acc1);
    }
    float tn[12];
    #pragma unroll
    for (int i=0;i<12;i++) tn[i] = el(sm.t, i, lane_n);
    float4 g1a, g1b;
    #pragma unroll
    for (int j=0;j<4;j++){
      int r = base0 + j;
      float z = b1V[r];
      const float* wr = W1V + r*12;
      #pragma unroll
      for (int i=0;i<12;i++) z = fmaf(wr[i], tn[i], z);
      (&g1a.x)[j] = sig_f(z) * acc0[j];
      r = base1 + j;
      z = b1V[r];
      wr = W1V + r*12;
      #pragma unroll
      for (int i=0;i<12;i++) z = fmaf(wr[i], tn[i], z);
      (&g1b.x)[j] = sig_f(z) * acc1[j];
    }
    stB4(sm.Bd[0][0], sm.Bd[0][1], lane_n, base0, g1a);
    stB4(sm.Bd[0][0], sm.Bd[0][1], lane_n, base1, g1b);
  }
  __syncthreads();
  // ---- dV/dt = W1V^T g1 via MFMA (wave 0; Bact dead -> dv overlay)
  if (w == 0){
    f32x4 acc = {0.f,0.f,0.f,0.f};
    #pragma unroll
    for (int q=0;q<4;q++){
      half8_t bh = ldB(sm.Bd[0][0], lane_n, q, quad);
      half8_t bl = ldB(sm.Bd[0][1], lane_n, q, quad);
      acc = mfma3(fW1Th[q*64+l], fW1Tl[q*64+l], bh, bl, acc);
    }
    int rb = quad*4;
    #pragma unroll
    for (int j=0;j<4;j++){
      int r = rb + j;
      if (r < 12) dvp[r][lane_n] = acc[j];
    }
  }
  __syncthreads();
  // ---- gravity
  if (tid < 96){
    int k = tid>>4, s = tid&15;
    sm.grav[k][s] = fmaf(el(sm.t,2*k,s), dvp[2*k+1][s],
                         -(el(sm.t,2*k+1,s)*dvp[2*k][s]));
  }
  __syncthreads();
  // ---- assembly + triangular solves + folded pre / final combine
  if (l < 4){
    int s = w*4 + l;
    float Lm[21];
    #pragma unroll
    for (int o=0;o<21;o++) Lm[o] = sm.y[o][s];
    float rhs[6];
    #pragma unroll
    for (int i=0;i<6;i++) rhs[i] = sm.tau[i][s] - sm.c[i][s] - sm.grav[i][s] - sm.f[i][s];
    float z[6];
    #pragma unroll
    for (int i=0;i<6;i++){
      float acc = rhs[i];
      for (int j=0;j<i;j++) acc = fmaf(-Lm[c_ROWOFF[i]+j], z[j], acc);
      z[i] = acc * __builtin_amdgcn_rcpf(Lm[c_ROWOFF[i]+i]);
    }
    float a[6];
    #pragma unroll
    for (int i=5;i>=0;i--){
      float acc = z[i];
      for (int j=i+1;j<6;j++) acc = fmaf(-Lm[c_ROWOFF[j]+i], a[j], acc);
      a[i] = acc * __builtin_amdgcn_rcpf(Lm[c_ROWOFF[i]+i]);
    }
    int b = s0 + s;
    const float* o = obs + b*12;
    if (stage < 3){
      float* kqd_out = kqd + stage*B6;
      #pragma unroll
      for (int i=0;i<6;i++) kqd_out[b*6+i] = a[i];
      unsigned mask = 0;
      #pragma unroll
      for (int i=0;i<6;i++){
        float q0=o[i], qd0=o[6+i];
        float q, qd;
        if (stage == 0){
          q  = q0 + 0.5f*DT*qd0;
          qd = qd0 + 0.5f*DT*a[i];
        } else if (stage == 1){
          float k1 = kqd[b*6+i];
          q  = q0 + 0.5f*DT*qd0 + 0.25f*DT*DT*k1;
          qd = qd0 + 0.5f*DT*a[i];
        } else {
          float k2 = kqd[B6 + b*6+i];
          q  = q0 + DT*qd0 + 0.5f*DT*DT*k2;
          qd = qd0 + DT*a[i];
        }
        q_cur[b*6+i]=q; qd_cur[b*6+i]=qd;
        float lo = c_LOWER[i]+0.1f, up = c_UPPER[i]-0.1f;
        if (q <= lo || q >= up) mask |= (1u<<i);
      }
      if (mask) atomicOr(viol + stage + 1, (int)mask);
    } else {
      // final RK4 combine: a == k4
      #pragma unroll
      for (int i=0;i<6;i++){
        float q0=o[i], qd0=o[6+i];
        float k1=kqd[b*6+i], k2=kqd[B6+b*6+i], k3=kqd[2*B6+b*6+i];
        float qn = q0 + DT*qd0 + (DT*DT/6.0f)*(k1+k2+k3);
        qn = fminf(fmaxf(qn, c_LOWER[i]), c_UPPER[i]);
        out[b*12+i] = qn;
        out[b*12+6+i] = qd0 + (DT/6.0f)*(k1 + 2.0f*k2 + 2.0f*k3 + a[i]);
      }
    }
  }
}

extern "C" void kernel_launch(void* const* d_in, const int* in_sizes, int n_in,
                              void* d_out, int out_size, void* d_ws, size_t ws_size,
                              hipStream_t stream) {
  const float* obs    = (const float*)d_in[0];
  const float* action = (const float*)d_in[1];
  const float* W1L = (const float*)d_in[2];  const float* b1L = (const float*)d_in[3];
  const float* W2L = (const float*)d_in[4];  const float* b2L = (const float*)d_in[5];
  const float* W3L = (const float*)d_in[6];  const float* b3L = (const float*)d_in[7];
  const float* W1V = (const float*)d_in[8];  const float* b1V = (const float*)d_in[9];
  const float* W2V = (const float*)d_in[10]; const float* b2V = (const float*)d_in[11];
  const float* W3V = (const float*)d_in[12]; // b3V unused: only grad of V needed

  float* ws = (float*)d_ws;
  _Float16* fragHi = (_Float16*)ws;            // 55296 halves
  _Float16* fragLo = fragHi + 55296;           // 55296 halves
  float* W1LT  = ws + 55296;                   // 1536
  float* W1VT  = W1LT + 1536;                  // 1536
  float* b3Lp  = W1VT + 1536;                  // 32
  float* q_cur  = b3Lp + 32;                   // B6
  float* qd_cur = q_cur + B6;                  // B6
  float* kqd    = qd_cur + B6;                 // 3*B6
  int*   viol   = (int*)(kqd + 3*B6);          // 4

  float* out = (float*)d_out;

  hipMemsetAsync(viol, 0, 16, stream);
  k_init<<<64,256,0,stream>>>(obs, W1L, W2L, W3L, W1V, W2V, b3L,
                              W1LT, W1VT, b3Lp, fragHi, fragLo, viol);
  for (int s = 0; s < 4; ++s){
    k_accel<<<1024,256,0,stream>>>(s, obs, q_cur, qd_cur, action,
        W1LT, b1L, b2L, b3Lp, W1VT, b1V, b2V, W3V, W1V,
        fragHi, fragLo, viol, kqd, out);
  }
}

// Round 12
// 272.787 us; speedup vs baseline: 4.2953x; 1.0102x over previous
//
#include <hip/hip_runtime.h>
#include <math.h>

#define BATCH 16384
#define B6 (BATCH*6)
#define DT 0.01f

using half8_t = __attribute__((ext_vector_type(8))) _Float16;
using half4_t = __attribute__((ext_vector_type(4))) _Float16;
using half2_t = __attribute__((ext_vector_type(2))) _Float16;
using f32x4   = __attribute__((ext_vector_type(4))) float;

__device__ __constant__ float c_LOWER[6]  = {-6.28f,-6.28f,-3.14f,-6.28f,-6.28f,-6.28f};
__device__ __constant__ float c_UPPER[6]  = { 6.28f, 6.28f, 3.14f, 6.28f, 6.28f, 6.28f};
__device__ __constant__ float c_EFFORT[6] = {150.0f,150.0f,150.0f,28.0f,28.0f,28.0f};
__device__ __constant__ int   c_ROWOFF[6] = {0,1,3,6,10,15};

__device__ __forceinline__ float sp_f(float z){
  return fmaxf(z,0.0f) + __logf(1.0f + __expf(-fabsf(z)));
}
__device__ __forceinline__ float sig_f(float z){
  return __builtin_amdgcn_rcpf(1.0f + __expf(-z));
}

__device__ __forceinline__ float4 f4all(float v){ return make_float4(v,v,v,v); }
__device__ __forceinline__ void fma4(float4& acc, float w, float4 a){
  acc.x=fmaf(w,a.x,acc.x); acc.y=fmaf(w,a.y,acc.y); acc.z=fmaf(w,a.z,acc.z); acc.w=fmaf(w,a.w,acc.w);
}
__device__ __forceinline__ float4 sp4(float4 z){
  return make_float4(sp_f(z.x),sp_f(z.y),sp_f(z.z),sp_f(z.w));
}
__device__ __forceinline__ float4 sig4(float4 z){
  return make_float4(sig_f(z.x),sig_f(z.y),sig_f(z.z),sig_f(z.w));
}

// XOR-swizzled accessors for sh_t [12][16] (r3/r4-verified conflict-free)
__device__ __forceinline__ const float4* chunkc(const float (*arr)[16], int n, int cc){
  return reinterpret_cast<const float4*>(&arr[n][4*(cc ^ ((n>>1)&3))]);
}
__device__ __forceinline__ float& el(float (*arr)[16], int n, int s){
  return arr[n][4*((s>>2) ^ ((n>>1)&3)) + (s&3)];
}

// ---- MFMA helpers --------------------------------------------------------
__device__ __forceinline__ f32x4 mfma3(half8_t ah, half8_t al, half8_t bh, half8_t bl, f32x4 acc){
  acc = __builtin_amdgcn_mfma_f32_16x16x32_f16(ah, bh, acc, 0,0,0);
  acc = __builtin_amdgcn_mfma_f32_16x16x32_f16(ah, bl, acc, 0,0,0);
  acc = __builtin_amdgcn_mfma_f32_16x16x32_f16(al, bh, acc, 0,0,0);
  return acc;
}
__device__ __forceinline__ half8_t ldB(const _Float16 (*B)[136], int n, int q, int quad){
  return *reinterpret_cast<const half8_t*>(&B[n][q*32 + quad*8]);
}
__device__ __forceinline__ void stB4(_Float16 (*Bh)[136], _Float16 (*Bl)[136], int n, int base, float4 v){
  half4_t hi, lo;
  const float* p = &v.x;
  #pragma unroll
  for (int j=0;j<4;j++){ hi[j] = (_Float16)p[j]; lo[j] = (_Float16)(p[j] - (float)hi[j]); }
  *reinterpret_cast<half4_t*>(&Bh[n][base]) = hi;
  *reinterpret_cast<half4_t*>(&Bl[n][base]) = lo;
}
__device__ __forceinline__ void stB2(_Float16 (*Bh)[136], _Float16 (*Bl)[136], int n, int k2, float a, float b){
  half2_t hi, lo;
  hi[0]=(_Float16)a; hi[1]=(_Float16)b;
  lo[0]=(_Float16)(a-(float)hi[0]); lo[1]=(_Float16)(b-(float)hi[1]);
  *reinterpret_cast<half2_t*>(&Bh[n][k2]) = hi;
  *reinterpret_cast<half2_t*>(&Bl[n][k2]) = lo;
}

// ---- shared-memory layout (union'd regions, ~33.2 KB) --------------------
struct SmemT {
  alignas(16) char u[8704];                 // Bact[2][16][136] | dy[42][17] | dv[12][17]
  alignas(16) _Float16 Bd[2][2][16][136];
  alignas(16) float t[12][16];
  float y[21][17];
  float s3[21][17];                         // sig(z3) stored once (r7-proven; identity recompute cost 6us/stage in r11)
  float wg[2][6][16];
  float qd[6][16], tau[6][16], f[6][16];
  float c[6][16], grav[6][16], v[6][16];
};

// ---------------- init: transposes + split-fp16 A-fragments + stage-0 viol
__global__ void __launch_bounds__(256) k_init(
    const float* __restrict__ obs,
    const float* __restrict__ W1L, const float* __restrict__ W2L,
    const float* __restrict__ W3L, const float* __restrict__ W1V,
    const float* __restrict__ W2V, const float* __restrict__ b3L,
    float* __restrict__ W1LT, float* __restrict__ W1VT, float* __restrict__ b3Lp,
    _Float16* __restrict__ fragHi, _Float16* __restrict__ fragLo, int* __restrict__ viol)
{
  int t = blockIdx.x*256 + threadIdx.x;
  if (t < 1536){ int i = t/128, k = t%128; W1LT[t] = W1L[k*12+i]; W1VT[t] = W1V[k*12+i]; }
  if (t < 32) b3Lp[t] = (t < 21) ? b3L[t] : 0.0f;
  if (t < 6912){
    int kind, f;
    if (t < 2048){ kind=0; f=t; }
    else if (t < 4096){ kind=1; f=t-2048; }
    else if (t < 6144){ kind=2; f=t-4096; }
    else if (t < 6656){ kind=3; f=t-6144; }
    else { kind=4; f=t-6656; }
    int tile = f>>8, q = (f>>6)&3, l = f&63, m = l&15, kq = 8*(l>>4);
    int off = (kind==0?0:kind==1?16384:kind==2?32768:kind==3?49152:53248) + f*8;
    #pragma unroll
    for (int e=0;e<8;e++){
      float v;
      int kk = 32*q + kq + e;
      if (kind==0)      v = W2L[(16*tile+m)*128 + kk];
      else if (kind==1) v = W2V[(16*tile+m)*128 + kk];
      else if (kind==2) v = W2V[kk*128 + (16*tile+m)];
      else if (kind==3){ int r = 16*tile+m; v = (r<21) ? W3L[r*128 + kk] : 0.0f; }
      else              v = (m<12) ? W1V[kk*12 + m] : 0.0f;
      _Float16 hi = (_Float16)v;
      _Float16 lo = (_Float16)(v - (float)hi);
      fragHi[off+e] = hi; fragLo[off+e] = lo;
    }
  }
  // stage-0 viol ballot (viol pre-zeroed by hipMemsetAsync)
  {
    unsigned mask = 0;
    const float* o = obs + t*12;
    #pragma unroll
    for (int i=0;i<6;i++){
      float q = o[i];
      float lo = c_LOWER[i]+0.1f, up = c_UPPER[i]-0.1f;
      if (q <= lo || q >= up) mask |= (1u<<i);
    }
    unsigned wm = 0;
    #pragma unroll
    for (int i=0;i<6;i++) if (__ballot((int)((mask>>i)&1u))) wm |= (1u<<i);
    if ((threadIdx.x & 63)==0 && wm) atomicOr(viol, (int)wm);
  }
}

// ---------------- per-stage accel kernel ----------------
// NOTE (learned r3/r9/r10): NO __launch_bounds__ min-waves hint and NO outer
// loops around this body — both explode VGPR use (64-pin spills / 256-VGPR
// liveness) and cost 2-4x in scratch traffic. Plain per-stage launches only.
__global__ void __launch_bounds__(256) k_accel(
    int stage,
    const float* __restrict__ obs,
    float* __restrict__ q_cur, float* __restrict__ qd_cur,
    const float* __restrict__ action,
    const float* __restrict__ W1LT, const float* __restrict__ b1L,
    const float* __restrict__ b2L,  const float* __restrict__ b3Lp,
    const float* __restrict__ W1VT, const float* __restrict__ b1V,
    const float* __restrict__ b2V,  const float* __restrict__ W3V,
    const float* __restrict__ W1V,
    const _Float16* __restrict__ fragHi, const _Float16* __restrict__ fragLo,
    int* __restrict__ viol, float* __restrict__ kqd, float* __restrict__ out)
{
  __shared__ SmemT sm;
  auto Bact = reinterpret_cast<_Float16 (*)[16][136]>(sm.u);  // [2][16][136]
  auto dyp  = reinterpret_cast<float (*)[17]>(sm.u);          // [42][17]
  auto dvp  = reinterpret_cast<float (*)[17]>(sm.u);          // [12][17]

  const int tid = threadIdx.x;
  const int l = tid & 63;
  const int w = tid >> 6;
  const int lane_n = l & 15;
  const int quad = l >> 4;
  const int base0 = w*16 + quad*4;
  const int base1 = (w+4)*16 + quad*4;
  const int s0 = blockIdx.x * 16;
  const int vm = __hip_atomic_load(viol + stage, __ATOMIC_RELAXED, __HIP_MEMORY_SCOPE_AGENT);

  const half8_t* fW2Lh  = (const half8_t*)(fragHi);
  const half8_t* fW2Ll  = (const half8_t*)(fragLo);
  const half8_t* fW2Vh  = (const half8_t*)(fragHi + 16384);
  const half8_t* fW2Vl  = (const half8_t*)(fragLo + 16384);
  const half8_t* fW2VTh = (const half8_t*)(fragHi + 32768);
  const half8_t* fW2VTl = (const half8_t*)(fragLo + 32768);
  const half8_t* fW3h   = (const half8_t*)(fragHi + 49152);
  const half8_t* fW3l   = (const half8_t*)(fragLo + 49152);
  const half8_t* fW1Th  = (const half8_t*)(fragHi + 53248);
  const half8_t* fW1Tl  = (const half8_t*)(fragLo + 53248);

  // ---- phase 0: trig, tau, constraint force
  if (tid < 96){
    int s = tid & 15, i = tid >> 4;
    float q, qdv;
    if (stage == 0){ q = obs[(s0+s)*12 + i]; qdv = obs[(s0+s)*12 + 6 + i]; }
    else           { q = q_cur[(s0+s)*6 + i]; qdv = qd_cur[(s0+s)*6 + i]; }
    sm.qd[i][s] = qdv;
    sm.tau[i][s] = action[(s0+s)*6+i] * c_EFFORT[i];
    el(sm.t, 2*i,   s) = cosf(q);
    el(sm.t, 2*i+1, s) = sinf(q);
    float lo = c_LOWER[i]+0.1f, up = c_UPPER[i]-0.1f;
    float barrier = -5.0f*(1.0f/(q-lo) - 1.0f/(up-q));
    float clip = (q<=lo)? c_EFFORT[i] : ((q>=up)? -c_EFFORT[i] : 0.0f);
    sm.f[i][s] = ((vm>>i)&1) ? clip : barrier;
    sm.c[i][s] = 0.0f;
  }
  __syncthreads();

  float4 s1a, s1b;
  // ---- L1L (VALU) -> Bact
  {
    float2 bb = *reinterpret_cast<const float2*>(b1L + 2*l);
    float4 z0 = f4all(bb.x), z1 = f4all(bb.y);
    #pragma unroll
    for (int i=0;i<12;i++){
      float2 wv = *reinterpret_cast<const float2*>(W1LT + i*128 + 2*l);
      float4 a = *chunkc(sm.t, i, w);
      fma4(z0, wv.x, a); fma4(z1, wv.y, a);
    }
    float4 h0 = sp4(z0), h1 = sp4(z1);
    s1a = sig4(z0); s1b = sig4(z1);
    #pragma unroll
    for (int j=0;j<4;j++)
      stB2(Bact[0], Bact[1], 4*w+j, 2*l, (&h0.x)[j], (&h1.x)[j]);
  }
  __syncthreads();

  float4 s2a, s2b;
  // ---- L2L MFMA + epilogue (h2 -> Bact in-place)
  {
    f32x4 acc0 = {0.f,0.f,0.f,0.f}, acc1 = {0.f,0.f,0.f,0.f};
    #pragma unroll
    for (int q=0;q<4;q++){
      half8_t bh = ldB(Bact[0], lane_n, q, quad);
      half8_t bl = ldB(Bact[1], lane_n, q, quad);
      acc0 = mfma3(fW2Lh[(w*4+q)*64+l],     fW2Ll[(w*4+q)*64+l],     bh, bl, acc0);
      acc1 = mfma3(fW2Lh[((w+4)*4+q)*64+l], fW2Ll[((w+4)*4+q)*64+l], bh, bl, acc1);
    }
    __syncthreads();
    float4 ba = *reinterpret_cast<const float4*>(b2L + base0);
    float4 bb = *reinterpret_cast<const float4*>(b2L + base1);
    float4 h2a, h2b;
    #pragma unroll
    for (int j=0;j<4;j++){
      float z = acc0[j] + (&ba.x)[j];
      (&h2a.x)[j] = sp_f(z); (&s2a.x)[j] = sig_f(z);
      z = acc1[j] + (&bb.x)[j];
      (&h2b.x)[j] = sp_f(z); (&s2b.x)[j] = sig_f(z);
    }
    stB4(Bact[0], Bact[1], lane_n, base0, h2a);
    stB4(Bact[0], Bact[1], lane_n, base1, h2b);
  }
  __syncthreads();

  // ---- L3 MFMA (waves 0,1) -> y and s3
  if (w < 2){
    f32x4 acc = {0.f,0.f,0.f,0.f};
    #pragma unroll
    for (int q=0;q<4;q++){
      half8_t bh = ldB(Bact[0], lane_n, q, quad);
      half8_t bl = ldB(Bact[1], lane_n, q, quad);
      acc = mfma3(fW3h[(w*4+q)*64+l], fW3l[(w*4+q)*64+l], bh, bl, acc);
    }
    int rb = w*16 + quad*4;
    #pragma unroll
    for (int j=0;j<4;j++){
      int r = rb + j;
      if (r < 21){
        float z = acc[j] + b3Lp[r];
        sm.y[r][lane_n]  = sp_f(z);
        sm.s3[r][lane_n] = sig_f(z);
      }
    }
  }
  __syncthreads();

  // ---- v = L^T qdot
  if (tid < 96){
    int s = tid & 15, jj = tid >> 4;
    float acc = 0.f;
    for (int i=jj;i<6;i++) acc = fmaf(sm.y[c_ROWOFF[i]+jj][s], sm.qd[i][s], acc);
    sm.v[jj][s] = acc;
  }

  // ---- tangent groups: dirs {2G, 2G+1}
  for (int G=0; G<3; ++G){
    #pragma unroll
    for (int d=0; d<2; ++d){
      int g = 2*G + d;
      float2 w0 = *reinterpret_cast<const float2*>(W1LT + (2*g)*128 + 2*l);
      float2 w1 = *reinterpret_cast<const float2*>(W1LT + (2*g+1)*128 + 2*l);
      float4 tc = *chunkc(sm.t, 2*g,   w);
      float4 ts = *chunkc(sm.t, 2*g+1, w);
      #pragma unroll
      for (int j=0;j<4;j++){
        float tcj = (&tc.x)[j], tsj = (&ts.x)[j];
        float d0 = (&s1a.x)[j]*(tcj*w1.x - tsj*w0.x);
        float d1 = (&s1b.x)[j]*(tcj*w1.y - tsj*w0.y);
        stB2(sm.Bd[d][0], sm.Bd[d][1], 4*w+j, 2*l, d0, d1);
      }
    }
    __syncthreads();
    f32x4 ta00={0.f,0.f,0.f,0.f}, ta01=ta00, ta10=ta00, ta11=ta00;
    #pragma unroll
    for (int q=0;q<4;q++){
      half8_t b0h = ldB(sm.Bd[0][0], lane_n, q, quad);
      half8_t b0l = ldB(sm.Bd[0][1], lane_n, q, quad);
      half8_t b1h = ldB(sm.Bd[1][0], lane_n, q, quad);
      half8_t b1l = ldB(sm.Bd[1][1], lane_n, q, quad);
      half8_t a0h = fW2Lh[(w*4+q)*64+l],     a0l = fW2Ll[(w*4+q)*64+l];
      half8_t a1h = fW2Lh[((w+4)*4+q)*64+l], a1l = fW2Ll[((w+4)*4+q)*64+l];
      ta00 = mfma3(a0h, a0l, b0h, b0l, ta00);
      ta01 = mfma3(a0h, a0l, b1h, b1l, ta01);
      ta10 = mfma3(a1h, a1l, b0h, b0l, ta10);
      ta11 = mfma3(a1h, a1l, b1h, b1l, ta11);
    }
    __syncthreads();
    {
      float4 v;
      #pragma unroll
      for (int j=0;j<4;j++) (&v.x)[j] = (&s2a.x)[j]*ta00[j];
      stB4(sm.Bd[0][0], sm.Bd[0][1], lane_n, base0, v);
      #pragma unroll
      for (int j=0;j<4;j++) (&v.x)[j] = (&s2b.x)[j]*ta10[j];
      stB4(sm.Bd[0][0], sm.Bd[0][1], lane_n, base1, v);
      #pragma unroll
      for (int j=0;j<4;j++) (&v.x)[j] = (&s2a.x)[j]*ta01[j];
      stB4(sm.Bd[1][0], sm.Bd[1][1], lane_n, base0, v);
      #pragma unroll
      for (int j=0;j<4;j++) (&v.x)[j] = (&s2b.x)[j]*ta11[j];
      stB4(sm.Bd[1][0], sm.Bd[1][1], lane_n, base1, v);
    }
    __syncthreads();
    {
      int d = w & 1, tt = w >> 1;
      f32x4 acc = {0.f,0.f,0.f,0.f};
      #pragma unroll
      for (int q=0;q<4;q++){
        half8_t bh = ldB(sm.Bd[d][0], lane_n, q, quad);
        half8_t bl = ldB(sm.Bd[d][1], lane_n, q, quad);
        acc = mfma3(fW3h[(tt*4+q)*64+l], fW3l[(tt*4+q)*64+l], bh, bl, acc);
      }
      int rb = tt*16 + quad*4;
      #pragma unroll
      for (int j=0;j<4;j++){
        int r = rb + j;
        if (r < 21) dyp[d*21 + r][lane_n] = sm.s3[r][lane_n] * acc[j];
      }
    }
    __syncthreads();
    if (tid < 32){
      int s = tid & 15, gg = tid >> 4;
      float qd[6];
      #pragma unroll
      for (int i=0;i<6;i++) qd[i] = sm.qd[i][s];
      float u[6];
      #pragma unroll
      for (int jj=0;jj<6;jj++){
        float acc = 0.f;
        for (int i=jj;i<6;i++) acc = fmaf(dyp[gg*21 + c_ROWOFF[i]+jj][s], qd[i], acc);
        u[jj] = acc;
      }
      #pragma unroll
      for (int i=0;i<6;i++){
        float acc = 0.f;
        for (int j=0;j<=i;j++){
          acc = fmaf(dyp[gg*21 + c_ROWOFF[i]+j][s], sm.v[j][s], acc);
          acc = fmaf(sm.y[c_ROWOFF[i]+j][s], u[j], acc);
        }
        sm.wg[gg][i][s] = acc;
      }
    }
    __syncthreads();
    if (tid < 96){
      int s = tid & 15, i = tid >> 4;
      float acc = sm.c[i][s];
      acc = fmaf(sm.qd[2*G][s],   sm.wg[0][i][s], acc);
      acc = fmaf(sm.qd[2*G+1][s], sm.wg[1][i][s], acc);
      int gi = i - 2*G;
      if (gi == 0 || gi == 1){
        float r = 0.f;
        #pragma unroll
        for (int j=0;j<6;j++) r = fmaf(sm.qd[j][s], sm.wg[gi][j][s], r);
        acc -= 0.5f*r;
      }
      sm.c[i][s] = acc;
    }
    __syncthreads();
  }

  // ---- V-net L1 (VALU) -> Bact (dy dead)
  {
    float2 bb = *reinterpret_cast<const float2*>(b1V + 2*l);
    float4 z0 = f4all(bb.x), z1 = f4all(bb.y);
    #pragma unroll
    for (int i=0;i<12;i++){
      float2 wv = *reinterpret_cast<const float2*>(W1VT + i*128 + 2*l);
      float4 a = *chunkc(sm.t, i, w);
      fma4(z0, wv.x, a); fma4(z1, wv.y, a);
    }
    float4 h0 = sp4(z0), h1 = sp4(z1);
    #pragma unroll
    for (int j=0;j<4;j++)
      stB2(Bact[0], Bact[1], 4*w+j, 2*l, (&h0.x)[j], (&h1.x)[j]);
  }
  __syncthreads();
  // ---- L2V MFMA; epilogue g2 = sig(z)*W3V -> Bact in-place
  {
    f32x4 acc0 = {0.f,0.f,0.f,0.f}, acc1 = {0.f,0.f,0.f,0.f};
    #pragma unroll
    for (int q=0;q<4;q++){
      half8_t bh = ldB(Bact[0], lane_n, q, quad);
      half8_t bl = ldB(Bact[1], lane_n, q, quad);
      acc0 = mfma3(fW2Vh[(w*4+q)*64+l],     fW2Vl[(w*4+q)*64+l],     bh, bl, acc0);
      acc1 = mfma3(fW2Vh[((w+4)*4+q)*64+l], fW2Vl[((w+4)*4+q)*64+l], bh, bl, acc1);
    }
    __syncthreads();
    float4 ba  = *reinterpret_cast<const float4*>(b2V + base0);
    float4 bb  = *reinterpret_cast<const float4*>(b2V + base1);
    float4 w3a = *reinterpret_cast<const float4*>(W3V + base0);
    float4 w3b = *reinterpret_cast<const float4*>(W3V + base1);
    float4 g2a, g2b;
    #pragma unroll
    for (int j=0;j<4;j++){
      (&g2a.x)[j] = sig_f(acc0[j] + (&ba.x)[j]) * (&w3a.x)[j];
      (&g2b.x)[j] = sig_f(acc1[j] + (&bb.x)[j]) * (&w3b.x)[j];
    }
    stB4(Bact[0], Bact[1], lane_n, base0, g2a);
    stB4(Bact[0], Bact[1], lane_n, base1, g2b);
  }
  __syncthreads();
  // ---- V bwd MFMA (A = W2V^T); epilogue: recompute s1V, g1 -> Bd[0]
  {
    f32x4 acc0 = {0.f,0.f,0.f,0.f}, acc1 = {0.f,0.f,0.f,0.f};
    #pragma unroll
    for (int q=0;q<4;q++){
      half8_t bh = ldB(Bact[0], lane_n, q, quad);
      half8_t bl = ldB(Bact[1], lane_n, q, quad);
      acc0 = mfma3(fW2VTh[(w*4+q)*64+l],     fW2VTl[(w*4+q)*64+l],     bh, bl, acc0);
      acc1 = mfma3(fW2VTh[((w+4)*4+q)*64+l], fW2VTl[((w+4)*4+q)*64+l], bh, bl, acc1);
    }
    float tn[12];
    #pragma unroll
    for (int i=0;i<12;i++) tn[i] = el(sm.t, i, lane_n);
    float4 g1a, g1b;
    #pragma unroll
    for (int j=0;j<4;j++){
      int r = base0 + j;
      float z = b1V[r];
      const float* wr = W1V + r*12;
      #pragma unroll
      for (int i=0;i<12;i++) z = fmaf(wr[i], tn[i], z);
      (&g1a.x)[j] = sig_f(z) * acc0[j];
      r = base1 + j;
      z = b1V[r];
      wr = W1V + r*12;
      #pragma unroll
      for (int i=0;i<12;i++) z = fmaf(wr[i], tn[i], z);
      (&g1b.x)[j] = sig_f(z) * acc1[j];
    }
    stB4(sm.Bd[0][0], sm.Bd[0][1], lane_n, base0, g1a);
    stB4(sm.Bd[0][0], sm.Bd[0][1], lane_n, base1, g1b);
  }
  __syncthreads();
  // ---- dV/dt = W1V^T g1 via MFMA (wave 0; Bact dead -> dv overlay)
  if (w == 0){
    f32x4 acc = {0.f,0.f,0.f,0.f};
    #pragma unroll
    for (int q=0;q<4;q++){
      half8_t bh = ldB(sm.Bd[0][0], lane_n, q, quad);
      half8_t bl = ldB(sm.Bd[0][1], lane_n, q, quad);
      acc = mfma3(fW1Th[q*64+l], fW1Tl[q*64+l], bh, bl, acc);
    }
    int rb = quad*4;
    #pragma unroll
    for (int j=0;j<4;j++){
      int r = rb + j;
      if (r < 12) dvp[r][lane_n] = acc[j];
    }
  }
  __syncthreads();
  // ---- gravity
  if (tid < 96){
    int k = tid>>4, s = tid&15;
    sm.grav[k][s] = fmaf(el(sm.t,2*k,s), dvp[2*k+1][s],
                         -(el(sm.t,2*k+1,s)*dvp[2*k][s]));
  }
  __syncthreads();
  // ---- assembly + triangular solves + folded pre / final combine
  if (l < 4){
    int s = w*4 + l;
    float Lm[21];
    #pragma unroll
    for (int o=0;o<21;o++) Lm[o] = sm.y[o][s];
    float rhs[6];
    #pragma unroll
    for (int i=0;i<6;i++) rhs[i] = sm.tau[i][s] - sm.c[i][s] - sm.grav[i][s] - sm.f[i][s];
    float z[6];
    #pragma unroll
    for (int i=0;i<6;i++){
      float acc = rhs[i];
      for (int j=0;j<i;j++) acc = fmaf(-Lm[c_ROWOFF[i]+j], z[j], acc);
      z[i] = acc * __builtin_amdgcn_rcpf(Lm[c_ROWOFF[i]+i]);
    }
    float a[6];
    #pragma unroll
    for (int i=5;i>=0;i--){
      float acc = z[i];
      for (int j=i+1;j<6;j++) acc = fmaf(-Lm[c_ROWOFF[j]+i], a[j], acc);
      a[i] = acc * __builtin_amdgcn_rcpf(Lm[c_ROWOFF[i]+i]);
    }
    int b = s0 + s;
    const float* o = obs + b*12;
    if (stage < 3){
      float* kqd_out = kqd + stage*B6;
      #pragma unroll
      for (int i=0;i<6;i++) kqd_out[b*6+i] = a[i];
      unsigned mask = 0;
      #pragma unroll
      for (int i=0;i<6;i++){
        float q0=o[i], qd0=o[6+i];
        float q, qd;
        if (stage == 0){
          q  = q0 + 0.5f*DT*qd0;
          qd = qd0 + 0.5f*DT*a[i];
        } else if (stage == 1){
          float k1 = kqd[b*6+i];
          q  = q0 + 0.5f*DT*qd0 + 0.25f*DT*DT*k1;
          qd = qd0 + 0.5f*DT*a[i];
        } else {
          float k2 = kqd[B6 + b*6+i];
          q  = q0 + DT*qd0 + 0.5f*DT*DT*k2;
          qd = qd0 + DT*a[i];
        }
        q_cur[b*6+i]=q; qd_cur[b*6+i]=qd;
        float lo = c_LOWER[i]+0.1f, up = c_UPPER[i]-0.1f;
        if (q <= lo || q >= up) mask |= (1u<<i);
      }
      if (mask) atomicOr(viol + stage + 1, (int)mask);
    } else {
      // final RK4 combine: a == k4
      #pragma unroll
      for (int i=0;i<6;i++){
        float q0=o[i], qd0=o[6+i];
        float k1=kqd[b*6+i], k2=kqd[B6+b*6+i], k3=kqd[2*B6+b*6+i];
        float qn = q0 + DT*qd0 + (DT*DT/6.0f)*(k1+k2+k3);
        qn = fminf(fmaxf(qn, c_LOWER[i]), c_UPPER[i]);
        out[b*12+i] = qn;
        out[b*12+6+i] = qd0 + (DT/6.0f)*(k1 + 2.0f*k2 + 2.0f*k3 + a[i]);
      }
    }
  }
}

extern "C" void kernel_launch(void* const* d_in, const int* in_sizes, int n_in,
                              void* d_out, int out_size, void* d_ws, size_t ws_size,
                              hipStream_t stream) {
  const float* obs    = (const float*)d_in[0];
  const float* action = (const float*)d_in[1];
  const float* W1L = (const float*)d_in[2];  const float* b1L = (const float*)d_in[3];
  const float* W2L = (const float*)d_in[4];  const float* b2L = (const float*)d_in[5];
  const float* W3L = (const float*)d_in[6];  const float* b3L = (const float*)d_in[7];
  const float* W1V = (const float*)d_in[8];  const float* b1V = (const float*)d_in[9];
  const float* W2V = (const float*)d_in[10]; const float* b2V = (const float*)d_in[11];
  const float* W3V = (const float*)d_in[12]; // b3V unused: only grad of V needed

  float* ws = (float*)d_ws;
  _Float16* fragHi = (_Float16*)ws;            // 55296 halves
  _Float16* fragLo = fragHi + 55296;           // 55296 halves
  float* W1LT  = ws + 55296;                   // 1536
  float* W1VT  = W1LT + 1536;                  // 1536
  float* b3Lp  = W1VT + 1536;                  // 32
  float* q_cur  = b3Lp + 32;                   // B6
  float* qd_cur = q_cur + B6;                  // B6
  float* kqd    = qd_cur + B6;                 // 3*B6
  int*   viol   = (int*)(kqd + 3*B6);          // 4

  float* out = (float*)d_out;

  hipMemsetAsync(viol, 0, 16, stream);
  k_init<<<64,256,0,stream>>>(obs, W1L, W2L, W3L, W1V, W2V, b3L,
                              W1LT, W1VT, b3Lp, fragHi, fragLo, viol);
  for (int s = 0; s < 4; ++s){
    k_accel<<<1024,256,0,stream>>>(s, obs, q_cur, qd_cur, action,
        W1LT, b1L, b2L, b3Lp, W1VT, b1V, b2V, W3V, W1V,
        fragHi, fragLo, viol, kqd, out);
  }
}